// Round 14
// baseline (268.025 us; speedup 1.0000x reference)
//
#include <hip/hip_runtime.h>
#include <math.h>

namespace {

constexpr int Bc = 4, Cc = 96, Hc = 56, Wc = 56;
constexpr int HWc = Hc * Wc;       // 3136
constexpr int Nc  = Bc * HWc;      // 12544
constexpr float EPSc = 1e-5f;

typedef __attribute__((ext_vector_type(8))) short bf16x8;
typedef __attribute__((ext_vector_type(4))) float f32x4;
typedef __attribute__((ext_vector_type(4))) unsigned int u32x4;

__device__ __forceinline__ unsigned short f2bf(float f) {
  union { float f; unsigned u; } x; x.f = f;
  unsigned r = x.u + 0x7fffu + ((x.u >> 16) & 1u);
  return (unsigned short)(r >> 16);
}
__device__ __forceinline__ float bf2f(unsigned short u) {
  union { unsigned u; float f; } x; x.u = (unsigned)u << 16; return x.f;
}
__device__ __forceinline__ float gelu_exact(float x) {
  return 0.5f * x * (1.0f + erff(x * 0.7071067811865475f));
}

// ---------------- LayerNorm over channel dim -> bf16 NHWC ----------------
__global__ __launch_bounds__(256) void k_ln(const float* __restrict__ x,
                                            const float* __restrict__ g,
                                            const float* __restrict__ b,
                                            unsigned short* __restrict__ outN) {
  int pos = blockIdx.x * 256 + threadIdx.x;
  int bb = pos / HWc, hw = pos % HWc;
  const float* xb = x + (size_t)bb * Cc * HWc + hw;
  float s = 0.f, s2 = 0.f;
  for (int c = 0; c < Cc; ++c) { float v = xb[c * HWc]; s += v; s2 += v * v; }
  float mu  = s * (1.f / Cc);
  float var = fmaxf(s2 * (1.f / Cc) - mu * mu, 0.f);
  float rs  = rsqrtf(var + EPSc);
  unsigned short* ob = outN + (size_t)pos * Cc;
  for (int q = 0; q < 12; ++q) {
    unsigned short t8[8];
#pragma unroll
    for (int j = 0; j < 8; ++j) {
      int c = q * 8 + j;
      t8[j] = f2bf((xb[c * HWc] - mu) * rs * g[c] + b[c]);
    }
    *reinterpret_cast<bf16x8*>(ob + q * 8) = *reinterpret_cast<const bf16x8*>(t8);
  }
}

// ---------------- weight pack: W[o][c][ky][kx] -> frag layout bf16 ----------------
template <int K_, int MTILES, int P>
__global__ __launch_bounds__(256) void k_pack_w(const float* __restrict__ wsrc,
                                                unsigned short* __restrict__ wpk) {
  constexpr int TOTAL = K_ * K_ * 3 * MTILES * 512;
  int idx = blockIdx.x * 256 + threadIdx.x;
  if (idx >= TOTAL) return;
  int j    = idx & 7;
  int lane = (idx >> 3) & 63;
  int t    = idx >> 9;             // (p*3+cc)*MTILES + mt
  int mt   = t % MTILES;
  int step = t / MTILES;
  int o = mt * 16 + (lane & 15);
  int k = step * 32 + ((lane >> 4) & 3) * 8 + j;
  int p = k / Cc, c = k % Cc;
  float v = 0.f;
  if (o < P) v = wsrc[(((size_t)o * Cc + c) * K_ + p / K_) * K_ + (p % K_)];
  wpk[idx] = f2bf(v);
}

// ---------------- depthwise weight transpose [C][KK] -> [KK][C] ----------------
__global__ __launch_bounds__(256) void k_pack_dwt(const float* __restrict__ dwsrc,
                                                  float* __restrict__ dwt, int KK) {
  int idx = blockIdx.x * 256 + threadIdx.x;
  if (idx >= KK * Cc) return;
  int p = idx / Cc, c = idx % Cc;
  dwt[idx] = dwsrc[c * KK + p];
}

// ---------------- pointwise 96x96 MFMA GEMM: bf16 NHWC in -> bf16 (padded) NHWC out ----------
template <int GELU, int PADP, int WP>
__global__ __launch_bounds__(256) void k_pwg(const unsigned short* __restrict__ inN,
                                             const unsigned short* __restrict__ wpk,
                                             const float* __restrict__ bq,
                                             unsigned short* __restrict__ outPad) {
  int lane = threadIdx.x & 63;
  int wv = threadIdx.x >> 6;
  int ng = wv & 1, mg = wv >> 1;
  int n = blockIdx.x * 32 + ng * 16 + (lane & 15);
  int ko = ((lane >> 4) & 3) * 8;
  const unsigned short* ib = inN + (size_t)n * Cc + ko;
  const unsigned short* wl = wpk + (size_t)lane * 8;
  f32x4 acc[3];
#pragma unroll
  for (int m = 0; m < 3; ++m) acc[m] = (f32x4){0.f, 0.f, 0.f, 0.f};
#pragma unroll
  for (int ks = 0; ks < 3; ++ks) {
    bf16x8 bf = *reinterpret_cast<const bf16x8*>(ib + ks * 32);
#pragma unroll
    for (int m = 0; m < 3; ++m) {
      bf16x8 af = *reinterpret_cast<const bf16x8*>(wl + (size_t)(ks * 6 + mg * 3 + m) * 512);
      acc[m] = __builtin_amdgcn_mfma_f32_16x16x32_bf16(af, bf, acc[m], 0, 0, 0);
    }
  }
  int bb = n / HWc, hw = n % HWc;
  int h = hw / Wc, w = hw % Wc;
  unsigned short* ob = outPad + (((size_t)bb * (Hc + 2 * PADP) + h + PADP) * WP + w + PADP) * Cc;
  int orow = ((lane >> 4) & 3) * 4;
#pragma unroll
  for (int m = 0; m < 3; ++m) {
    int o0 = (mg * 3 + m) * 16 + orow;
    float4 bv = *reinterpret_cast<const float4*>(bq + o0);
    unsigned short t4[4];
#pragma unroll
    for (int j = 0; j < 4; ++j) {
      float r = acc[m][j] + ((const float*)&bv)[j];
      if (GELU) r = gelu_exact(r);
      t4[j] = f2bf(r);
    }
    *reinterpret_cast<uint2*>(ob + o0) = *reinterpret_cast<const uint2*>(t4);
  }
}

// ---------------- combine: GEMM p2w over (u*A) + yln + ls1, residual out, y2 NHWC ----------
template <int UPADP, int UWP>
__global__ __launch_bounds__(256) void k_comb(const unsigned short* __restrict__ uPad,
                                              const unsigned short* __restrict__ An,
                                              const unsigned short* __restrict__ wpk,
                                              const float* __restrict__ bq,
                                              const unsigned short* __restrict__ ylnN,
                                              const float* __restrict__ ls1q,
                                              const float* __restrict__ x,
                                              float* __restrict__ out,
                                              unsigned short* __restrict__ y2N) {
  int lane = threadIdx.x & 63;
  int wv = threadIdx.x >> 6;
  int ng = wv & 1, mg = wv >> 1;
  int n = blockIdx.x * 32 + ng * 16 + (lane & 15);
  int ko = ((lane >> 4) & 3) * 8;
  int bb = n / HWc, hw = n % HWc;
  int h = hw / Wc, w = hw % Wc;
  const unsigned short* ub = uPad + (((size_t)bb * (Hc + 2 * UPADP) + h + UPADP) * UWP + w + UPADP) * Cc + ko;
  const unsigned short* ab = An + (size_t)n * Cc + ko;
  const unsigned short* wl = wpk + (size_t)lane * 8;
  f32x4 acc[3];
#pragma unroll
  for (int m = 0; m < 3; ++m) acc[m] = (f32x4){0.f, 0.f, 0.f, 0.f};
#pragma unroll
  for (int ks = 0; ks < 3; ++ks) {
    bf16x8 uv = *reinterpret_cast<const bf16x8*>(ub + ks * 32);
    bf16x8 av = *reinterpret_cast<const bf16x8*>(ab + ks * 32);
    union { bf16x8 v; unsigned short s[8]; } uu, aa, gg;
    uu.v = uv; aa.v = av;
#pragma unroll
    for (int j = 0; j < 8; ++j) gg.s[j] = f2bf(bf2f(uu.s[j]) * bf2f(aa.s[j]));
#pragma unroll
    for (int m = 0; m < 3; ++m) {
      bf16x8 af = *reinterpret_cast<const bf16x8*>(wl + (size_t)(ks * 6 + mg * 3 + m) * 512);
      acc[m] = __builtin_amdgcn_mfma_f32_16x16x32_bf16(af, gg.v, acc[m], 0, 0, 0);
    }
  }
  int orow = ((lane >> 4) & 3) * 4;
  const float* xb = x + (size_t)bb * Cc * HWc + hw;
  float* ob = out + (size_t)bb * Cc * HWc + hw;
#pragma unroll
  for (int m = 0; m < 3; ++m) {
    int o0 = (mg * 3 + m) * 16 + orow;
    float4 bv = *reinterpret_cast<const float4*>(bq + o0);
    float4 lv = *reinterpret_cast<const float4*>(ls1q + o0);
    uint2 yl = *reinterpret_cast<const uint2*>(ylnN + (size_t)n * Cc + o0);
    unsigned short yl4[4];
    *reinterpret_cast<uint2*>(yl4) = yl;
    unsigned short t4[4];
#pragma unroll
    for (int j = 0; j < 4; ++j) {
      float t = acc[m][j] + ((const float*)&bv)[j] + bf2f(yl4[j]);
      float y2 = ((const float*)&lv)[j] * t;
      t4[j] = f2bf(y2);
      ob[(size_t)(o0 + j) * HWc] = xb[(size_t)(o0 + j) * HWc] + y2;
    }
    *reinterpret_cast<uint2*>(y2N + (size_t)n * Cc + o0) = *reinterpret_cast<const uint2*>(t4);
  }
}

// ---------------- implicit-GEMM MFMA conv v8: LDS double-buffered tap pipeline ----------
// block 256 = 4 waves; block owns 128 positions x full M. Per tap: stage A-slab (wpk) and
// B-slab (input pixels) into LDS; compute from LDS; next tap's global loads issued before
// compute (2-phase T3 pipeline, one barrier per tap). grid: (Nc/128, SPLIT).
template <int K_, int DIL_, int MTILES, int P, int PADP, int WP, int PSTR, int SPLIT>
__global__ __launch_bounds__(256) void k_conv_lds(const unsigned short* __restrict__ inp,
                                                  const unsigned short* __restrict__ wpk,
                                                  const float* __restrict__ bq,
                                                  float* __restrict__ dstT) {
  constexpr int KK = K_ * K_;
  constexpr int KKb = KK / SPLIT, KKr = KK % SPLIT;
  constexpr int HP = Hc + 2 * PADP;
  constexpr int ASH = 3 * MTILES * 512;   // shorts per A tap-slab
  constexpr int BSTR = 104;               // shorts per position row (192B data + 16B pad)
  constexpr int BSH = 128 * BSTR;
  constexpr int ACH = ASH / 8;            // 16B chunks in A slab
  constexpr int BCH = 128 * 13;
  constexpr int TOT = ACH + BCH;
  constexpr int ITERS = (TOT + 255) / 256;
  __shared__ unsigned short smem[2][ASH + BSH];

  int tid = threadIdx.x;
  int lane = tid & 63;
  int wv = tid >> 6;
  int sp = blockIdx.y;
  int p0 = sp * KKb + min(sp, KKr);
  int pcnt = KKb + (sp < KKr ? 1 : 0);
  int n0 = blockIdx.x * 128;

  // per-thread staging descriptors (static arrays, unrolled indexing)
  const unsigned short* gbase[ITERS];
  int ldsOff[ITERS];
  int isA[ITERS];
#pragma unroll
  for (int it = 0; it < ITERS; ++it) {
    int c = tid + it * 256;
    if (c < ACH) {
      gbase[it] = wpk + (size_t)c * 8;
      ldsOff[it] = c * 8;
      isA[it] = 1;
    } else if (c < TOT) {
      int bc = c - ACH;
      int pl = bc / 13, sub = bc % 13;
      int subc = min(sub, 11);
      int n = n0 + pl;
      int b = n / HWc, hw = n % HWc, h = hw / Wc, w = hw % Wc;
      gbase[it] = inp + ((size_t)b * HP * WP + (size_t)h * WP + w) * Cc + subc * 8;
      ldsOff[it] = ASH + pl * BSTR + sub * 8;
      isA[it] = 0;
    } else {
      gbase[it] = nullptr;
      ldsOff[it] = 0;
      isA[it] = 0;
    }
  }

  u32x4 reg[ITERS];
  // prologue: tap p0 -> buf0
  {
    size_t ta = (size_t)p0 * ASH;
    size_t tb = (size_t)((p0 / K_) * DIL_ * WP + (p0 % K_) * DIL_) * Cc;
#pragma unroll
    for (int it = 0; it < ITERS; ++it)
      if (gbase[it]) reg[it] = *reinterpret_cast<const u32x4*>(gbase[it] + (isA[it] ? ta : tb));
#pragma unroll
    for (int it = 0; it < ITERS; ++it)
      if (gbase[it]) *reinterpret_cast<u32x4*>(&smem[0][ldsOff[it]]) = reg[it];
  }

  f32x4 acc[MTILES][2];
#pragma unroll
  for (int mt = 0; mt < MTILES; ++mt) {
    acc[mt][0] = (f32x4){0.f, 0.f, 0.f, 0.f};
    acc[mt][1] = (f32x4){0.f, 0.f, 0.f, 0.f};
  }

  int posl0 = wv * 32 + (lane & 15);
  int co = ((lane >> 4) & 3) * 8;
  int cur = 0;
  for (int pi = 0; pi < pcnt; ++pi) {
    __syncthreads();
    bool more = (pi + 1 < pcnt);
    if (more) {
      int pn = p0 + pi + 1;
      size_t ta = (size_t)pn * ASH;
      size_t tb = (size_t)((pn / K_) * DIL_ * WP + (pn % K_) * DIL_) * Cc;
#pragma unroll
      for (int it = 0; it < ITERS; ++it)
        if (gbase[it]) reg[it] = *reinterpret_cast<const u32x4*>(gbase[it] + (isA[it] ? ta : tb));
    }
    const unsigned short* sA = smem[cur];
    const unsigned short* sB = smem[cur] + ASH;
#pragma unroll
    for (int cc = 0; cc < 3; ++cc) {
      bf16x8 B0 = *reinterpret_cast<const bf16x8*>(sB + posl0 * BSTR + co + cc * 32);
      bf16x8 B1 = *reinterpret_cast<const bf16x8*>(sB + (posl0 + 16) * BSTR + co + cc * 32);
#pragma unroll
      for (int mt = 0; mt < MTILES; ++mt) {
        bf16x8 A = *reinterpret_cast<const bf16x8*>(sA + (cc * MTILES + mt) * 512 + lane * 8);
        acc[mt][0] = __builtin_amdgcn_mfma_f32_16x16x32_bf16(A, B0, acc[mt][0], 0, 0, 0);
        acc[mt][1] = __builtin_amdgcn_mfma_f32_16x16x32_bf16(A, B1, acc[mt][1], 0, 0, 0);
      }
    }
    if (more) {
#pragma unroll
      for (int it = 0; it < ITERS; ++it)
        if (gbase[it]) *reinterpret_cast<u32x4*>(&smem[cur ^ 1][ldsOff[it]]) = reg[it];
    }
    cur ^= 1;
  }

  float* dsp = dstT + (size_t)sp * Nc * PSTR;
  int orow = ((lane >> 4) & 3) * 4;
#pragma unroll
  for (int mt = 0; mt < MTILES; ++mt) {
#pragma unroll
    for (int nt = 0; nt < 2; ++nt) {
      float4 st;
#pragma unroll
      for (int j = 0; j < 4; ++j) {
        int o = mt * 16 + orow + j;
        float bias = (sp == 0 && o < P) ? bq[o] : 0.f;
        ((float*)&st)[j] = acc[mt][nt][j] + bias;
      }
      int n = n0 + posl0 + nt * 16;
      *reinterpret_cast<float4*>(dsp + (size_t)n * PSTR + mt * 16 + orow) = st;
    }
  }
}

// ---------------- meta precompute: merge K-split partials -> packed 16B meta ----------
template <int K_, int DIL_, int PAD_, int PSTR, int NSUM>
__global__ __launch_bounds__(256) void k_meta(const float* __restrict__ offT,
                                              uint4* __restrict__ meta) {
  constexpr int KK = K_ * K_;
  int idx = blockIdx.x * 256 + threadIdx.x;
  if (idx >= Nc * KK) return;
  int p = idx % KK, pos = idx / KK;
  int hw = pos % HWc;
  int h = hw / Wc, w = hw % Wc;
  const float* ob = offT + (size_t)pos * PSTR + 2 * p;
  float oy = ob[0], ox = ob[1];
#pragma unroll
  for (int q = 1; q < NSUM; ++q) {
    oy += ob[(size_t)q * Nc * PSTR];
    ox += ob[(size_t)q * Nc * PSTR + 1];
  }
  float py = (float)(h + (p / K_) * DIL_ - PAD_) + oy;
  float px = (float)(w + (p % K_) * DIL_ - PAD_) + ox;
  float y0f = floorf(py), x0f = floorf(px);
  float wy = py - y0f, wx = px - x0f;
  int y0 = (int)y0f, x0 = (int)x0f;
  int y1 = y0 + 1, x1 = x0 + 1;
  bool y0v = (unsigned)y0 < (unsigned)Hc, y1v = (unsigned)y1 < (unsigned)Hc;
  bool x0v = (unsigned)x0 < (unsigned)Wc, x1v = (unsigned)x1 < (unsigned)Wc;
  int y0c = min(max(y0, 0), Hc - 1), y1c = min(max(y1, 0), Hc - 1);
  int x0c = min(max(x0, 0), Wc - 1), x1c = min(max(x1, 0), Wc - 1);
  float w00 = (y0v && x0v) ? (1.f - wy) * (1.f - wx) : 0.f;
  float w01 = (y0v && x1v) ? (1.f - wy) * wx : 0.f;
  float w10 = (y1v && x0v) ? wy * (1.f - wx) : 0.f;
  float w11 = (y1v && x1v) ? wy * wx : 0.f;
  uint4 m;
  m.x = (unsigned)(y0c | (y1c << 6) | (x0c << 12) | (x1c << 18));
  m.y = 0;
  m.z = (unsigned)f2bf(w00) | ((unsigned)f2bf(w01) << 16);
  m.w = (unsigned)f2bf(w10) | ((unsigned)f2bf(w11) << 16);
  meta[idx] = m;
}

// ---------------- deformable depthwise v3: 4 ch/thread, packed meta, dwt in LDS ----------
template <int K_, int IPADP, int IWP, int OPADP, int OWP>
__global__ __launch_bounds__(256) void k_deform3(const unsigned short* __restrict__ srcT,
                                                 const uint4* __restrict__ meta,
                                                 const float* __restrict__ dwt,
                                                 const float* __restrict__ dbq,
                                                 unsigned short* __restrict__ dstPad) {
  constexpr int KK = K_ * K_;
  constexpr int IHP = Hc + 2 * IPADP;
  __shared__ float sdwt[KK * Cc];
  for (int i = threadIdx.x; i < KK * Cc; i += 256) sdwt[i] = dwt[i];
  __syncthreads();

  int tid = blockIdx.x * 256 + threadIdx.x;      // Nc*24 threads
  int cg = tid % 24;
  int pos = tid / 24;
  int c = cg * 4;
  int bb = pos / HWc, hw = pos % HWc;
  int h = hw / Wc, w = hw % Wc;
  const unsigned short* sb = srcT + ((size_t)bb * IHP * IWP + IPADP * IWP + IPADP) * Cc + c;
  const uint4* mt = meta + (size_t)pos * KK;
  float ac0 = 0.f, ac1 = 0.f, ac2 = 0.f, ac3 = 0.f;

  constexpr int BT = 4;
  int p = 0;
  for (; p + BT <= KK; p += BT) {
    uint4 m[BT];
#pragma unroll
    for (int i = 0; i < BT; ++i) m[i] = mt[p + i];
    uint2 v[BT][4];
#pragma unroll
    for (int i = 0; i < BT; ++i) {
      unsigned ix = m[i].x;
      int y0 = (int)(ix & 63u), y1 = (int)((ix >> 6) & 63u);
      int x0 = (int)((ix >> 12) & 63u), x1 = (int)((ix >> 18) & 63u);
      const unsigned short* r0 = sb + (size_t)(y0 * IWP) * Cc;
      const unsigned short* r1 = sb + (size_t)(y1 * IWP) * Cc;
      v[i][0] = *reinterpret_cast<const uint2*>(r0 + x0 * Cc);
      v[i][1] = *reinterpret_cast<const uint2*>(r0 + x1 * Cc);
      v[i][2] = *reinterpret_cast<const uint2*>(r1 + x0 * Cc);
      v[i][3] = *reinterpret_cast<const uint2*>(r1 + x1 * Cc);
    }
#pragma unroll
    for (int i = 0; i < BT; ++i) {
      float w00 = bf2f((unsigned short)(m[i].z & 0xffffu));
      float w01 = bf2f((unsigned short)(m[i].z >> 16));
      float w10 = bf2f((unsigned short)(m[i].w & 0xffffu));
      float w11 = bf2f((unsigned short)(m[i].w >> 16));
      float4 d = *reinterpret_cast<const float4*>(&sdwt[(p + i) * Cc + c]);
#pragma unroll
      for (int j = 0; j < 2; ++j) {
        unsigned u00 = ((const unsigned*)&v[i][0])[j];
        unsigned u01 = ((const unsigned*)&v[i][1])[j];
        unsigned u10 = ((const unsigned*)&v[i][2])[j];
        unsigned u11 = ((const unsigned*)&v[i][3])[j];
        union { unsigned u; float f; } a0_, b0_, a1_, b1_, a2_, b2_, a3_, b3_;
        a0_.u = u00 << 16; b0_.u = u00 & 0xffff0000u;
        a1_.u = u01 << 16; b1_.u = u01 & 0xffff0000u;
        a2_.u = u10 << 16; b2_.u = u10 & 0xffff0000u;
        a3_.u = u11 << 16; b3_.u = u11 & 0xffff0000u;
        float lo = w00 * a0_.f + w01 * a1_.f + w10 * a2_.f + w11 * a3_.f;
        float hi = w00 * b0_.f + w01 * b1_.f + w10 * b2_.f + w11 * b3_.f;
        if (j == 0) { ac0 += lo * d.x; ac1 += hi * d.y; }
        else        { ac2 += lo * d.z; ac3 += hi * d.w; }
      }
    }
  }
  // tail (KK % 4 == 1 for K=5,7)
  {
    uint4 m = mt[p];
    unsigned ix = m.x;
    int y0 = (int)(ix & 63u), y1 = (int)((ix >> 6) & 63u);
    int x0 = (int)((ix >> 12) & 63u), x1 = (int)((ix >> 18) & 63u);
    const unsigned short* r0 = sb + (size_t)(y0 * IWP) * Cc;
    const unsigned short* r1 = sb + (size_t)(y1 * IWP) * Cc;
    uint2 v0 = *reinterpret_cast<const uint2*>(r0 + x0 * Cc);
    uint2 v1 = *reinterpret_cast<const uint2*>(r0 + x1 * Cc);
    uint2 v2 = *reinterpret_cast<const uint2*>(r1 + x0 * Cc);
    uint2 v3 = *reinterpret_cast<const uint2*>(r1 + x1 * Cc);
    float w00 = bf2f((unsigned short)(m.z & 0xffffu));
    float w01 = bf2f((unsigned short)(m.z >> 16));
    float w10 = bf2f((unsigned short)(m.w & 0xffffu));
    float w11 = bf2f((unsigned short)(m.w >> 16));
    float4 d = *reinterpret_cast<const float4*>(&sdwt[p * Cc + c]);
#pragma unroll
    for (int j = 0; j < 2; ++j) {
      unsigned u00 = ((const unsigned*)&v0)[j];
      unsigned u01 = ((const unsigned*)&v1)[j];
      unsigned u10 = ((const unsigned*)&v2)[j];
      unsigned u11 = ((const unsigned*)&v3)[j];
      union { unsigned u; float f; } a0_, b0_, a1_, b1_, a2_, b2_, a3_, b3_;
      a0_.u = u00 << 16; b0_.u = u00 & 0xffff0000u;
      a1_.u = u01 << 16; b1_.u = u01 & 0xffff0000u;
      a2_.u = u10 << 16; b2_.u = u10 & 0xffff0000u;
      a3_.u = u11 << 16; b3_.u = u11 & 0xffff0000u;
      float lo = w00 * a0_.f + w01 * a1_.f + w10 * a2_.f + w11 * a3_.f;
      float hi = w00 * b0_.f + w01 * b1_.f + w10 * b2_.f + w11 * b3_.f;
      if (j == 0) { ac0 += lo * d.x; ac1 += hi * d.y; }
      else        { ac2 += lo * d.z; ac3 += hi * d.w; }
    }
  }

  unsigned short t4[4] = {f2bf(ac0 + dbq[c]), f2bf(ac1 + dbq[c + 1]),
                          f2bf(ac2 + dbq[c + 2]), f2bf(ac3 + dbq[c + 3])};
  unsigned short* tb = dstPad + (((size_t)bb * (Hc + 2 * OPADP) + h + OPADP) * OWP + w + OPADP) * Cc + c;
  *reinterpret_cast<uint2*>(tb) = *reinterpret_cast<const uint2*>(t4);
}

// ---------------- MLP: LN2 + f1 (96->4), y2 in bf16 NHWC ----------------
__global__ __launch_bounds__(256) void k_mlp1(const unsigned short* __restrict__ y2N,
                                              const float* __restrict__ g,
                                              const float* __restrict__ b,
                                              const float* __restrict__ f1wq,
                                              const float* __restrict__ f1bq,
                                              float* __restrict__ z4) {
  int pos = blockIdx.x * 256 + threadIdx.x;
  int bb = pos / HWc, hw = pos % HWc;
  const unsigned short* yb = y2N + (size_t)pos * Cc;
  float vv[96];
  float s = 0.f, s2 = 0.f;
#pragma unroll
  for (int q = 0; q < 12; ++q) {
    bf16x8 t = *reinterpret_cast<const bf16x8*>(yb + q * 8);
    union { bf16x8 v; unsigned short s[8]; } u; u.v = t;
#pragma unroll
    for (int j = 0; j < 8; ++j) {
      float f = bf2f(u.s[j]);
      vv[q * 8 + j] = f; s += f; s2 += f * f;
    }
  }
  float mu  = s * (1.f / Cc);
  float var = fmaxf(s2 * (1.f / Cc) - mu * mu, 0.f);
  float rs  = rsqrtf(var + EPSc);
  float a0 = 0.f, a1 = 0.f, a2 = 0.f, a3 = 0.f;
#pragma unroll
  for (int c = 0; c < 96; ++c) {
    float t = (vv[c] - mu) * rs * g[c] + b[c];
    a0 += t * f1wq[0 * Cc + c];
    a1 += t * f1wq[1 * Cc + c];
    a2 += t * f1wq[2 * Cc + c];
    a3 += t * f1wq[3 * Cc + c];
  }
  float* zb = z4 + (size_t)bb * 4 * HWc + hw;
  zb[0 * HWc] = a0 + f1bq[0];
  zb[1 * HWc] = a1 + f1bq[1];
  zb[2 * HWc] = a2 + f1bq[2];
  zb[3 * HWc] = a3 + f1bq[3];
}

// ---------------- MLP: depthwise 3x3 (4 ch) + GELU ----------------
__global__ __launch_bounds__(256) void k_mlp_dw(const float* __restrict__ z4,
                                                const float* __restrict__ dwwq,
                                                const float* __restrict__ dwbq,
                                                float* __restrict__ z4b) {
  int tid = blockIdx.x * 256 + threadIdx.x;
  int hw = tid % HWc;
  int bj = tid / HWc;
  int j = bj % 4;
  int h = hw / Wc, w = hw % Wc;
  const float* zb = z4 + (size_t)bj * HWc;
  float s = 0.f;
#pragma unroll
  for (int ky = 0; ky < 3; ++ky) {
    int y = h + ky - 1;
    if ((unsigned)y >= (unsigned)Hc) continue;
#pragma unroll
    for (int kx = 0; kx < 3; ++kx) {
      int x = w + kx - 1;
      if ((unsigned)x >= (unsigned)Wc) continue;
      s += zb[y * Wc + x] * dwwq[j * 9 + ky * 3 + kx];
    }
  }
  z4b[tid] = gelu_exact(s + dwbq[j]);
}

// ---------------- MLP: f2 (4->96) + ls2 + residual add into out ----------------
__global__ __launch_bounds__(256) void k_mlp2(const float* __restrict__ z4b,
                                              const float* __restrict__ f2wq,
                                              const float* __restrict__ f2bq,
                                              const float* __restrict__ ls2q,
                                              float* __restrict__ out) {
  int pos = blockIdx.x * 256 + threadIdx.x;
  int bb = pos / HWc, hw = pos % HWc;
  const float* zb = z4b + (size_t)bb * 4 * HWc + hw;
  float z0 = zb[0 * HWc], z1 = zb[1 * HWc], z2 = zb[2 * HWc], z3 = zb[3 * HWc];
  float* ob = out + (size_t)bb * Cc * HWc + hw;
  for (int o = 0; o < Cc; ++o) {
    float s = f2bq[o] + z0 * f2wq[o * 4 + 0] + z1 * f2wq[o * 4 + 1]
                      + z2 * f2wq[o * 4 + 2] + z3 * f2wq[o * 4 + 3];
    ob[o * HWc] += ls2q[o] * s;
  }
}

}  // namespace

extern "C" void kernel_launch(void* const* d_in, const int* in_sizes, int n_in,
                              void* d_out, int out_size, void* d_ws, size_t ws_size,
                              hipStream_t stream) {
  (void)in_sizes; (void)n_in; (void)out_size; (void)ws_size;
  const float* x   = (const float*)d_in[0];
  const float* g1n = (const float*)d_in[1];
  const float* b1n = (const float*)d_in[2];
  const float* p1w = (const float*)d_in[3];
  const float* p1b = (const float*)d_in[4];
  const float* o0w = (const float*)d_in[5];
  const float* o0b = (const float*)d_in[6];
  const float* d0w = (const float*)d_in[7];
  const float* d0b = (const float*)d_in[8];
  const float* o1w = (const float*)d_in[9];
  const float* o1b = (const float*)d_in[10];
  const float* d1w = (const float*)d_in[11];
  const float* d1b = (const float*)d_in[12];
  const float* c1w = (const float*)d_in[13];
  const float* c1b = (const float*)d_in[14];
  const float* p2w = (const float*)d_in[15];
  const float* p2b = (const float*)d_in[16];
  const float* ls1 = (const float*)d_in[17];
  const float* g2n = (const float*)d_in[18];
  const float* b2n = (const float*)d_in[19];
  const float* f1w = (const float*)d_in[20];
  const float* f1b = (const float*)d_in[21];
  const float* dww = (const float*)d_in[22];
  const float* dwb = (const float*)d_in[23];
  const float* f2w = (const float*)d_in[24];
  const float* f2b = (const float*)d_in[25];
  const float* ls2 = (const float*)d_in[26];
  float* out = (float*)d_out;
  float* ws  = (float*)d_ws;

  float* off0t = ws;                                  size_t o_ = (size_t)2 * Nc * 64;
  float* off1t = ws + o_;                             o_ += (size_t)2 * Nc * 112;
  float* z4    = ws + o_;                             o_ += (size_t)Bc * 4 * HWc;
  float* z4b   = ws + o_;                             o_ += (size_t)Bc * 4 * HWc;
  float* dwt0  = ws + o_;                             o_ += 25 * Cc;
  float* dwt1  = ws + o_;                             o_ += 49 * Cc + 4;
  o_ = (o_ + 3) & ~(size_t)3;
  uint4* metaM0 = (uint4*)(ws + o_);                  o_ += (size_t)Nc * 25 * 4;
  uint4* metaM1 = (uint4*)(ws + o_);                  o_ += (size_t)Nc * 49 * 4;
  unsigned short* yln_n  = (unsigned short*)(ws + o_); o_ += (size_t)Nc * Cc / 2;
  unsigned short* a1_n   = (unsigned short*)(ws + o_); o_ += (size_t)Nc * Cc / 2;
  unsigned short* A_n    = (unsigned short*)(ws + o_); o_ += (size_t)Nc * Cc / 2;
  unsigned short* y2_n   = (unsigned short*)(ws + o_); o_ += (size_t)Nc * Cc / 2;
  unsigned short* u_pad  = (unsigned short*)(ws + o_); o_ += (size_t)Bc * 60 * 60 * Cc / 2;
  unsigned short* a0_pad = (unsigned short*)(ws + o_); o_ += (size_t)Bc * 74 * 74 * Cc / 2;
  unsigned short* wpk0   = (unsigned short*)(ws + o_); o_ += (size_t)25 * 3 * 4 * 512 / 2;
  unsigned short* wpk1   = (unsigned short*)(ws + o_); o_ += (size_t)49 * 3 * 7 * 512 / 2;
  unsigned short* wpkp1  = (unsigned short*)(ws + o_); o_ += (size_t)3 * 6 * 512 / 2;
  unsigned short* wpkc1  = (unsigned short*)(ws + o_); o_ += (size_t)3 * 6 * 512 / 2;
  unsigned short* wpkp2  = (unsigned short*)(ws + o_); o_ += (size_t)3 * 6 * 512 / 2;

  dim3 b256(256, 1, 1);

  hipMemsetAsync(u_pad, 0, (size_t)Bc * 60 * 60 * Cc * sizeof(unsigned short), stream);
  hipMemsetAsync(a0_pad, 0, (size_t)Bc * 74 * 74 * Cc * sizeof(unsigned short), stream);
  hipLaunchKernelGGL((k_pack_w<5, 4, 50>), dim3((25 * 3 * 4 * 512 + 255) / 256), b256, 0, stream, o0w, wpk0);
  hipLaunchKernelGGL((k_pack_w<7, 7, 98>), dim3((49 * 3 * 7 * 512 + 255) / 256), b256, 0, stream, o1w, wpk1);
  hipLaunchKernelGGL((k_pack_w<1, 6, 96>), dim3((3 * 6 * 512 + 255) / 256), b256, 0, stream, p1w, wpkp1);
  hipLaunchKernelGGL((k_pack_w<1, 6, 96>), dim3((3 * 6 * 512 + 255) / 256), b256, 0, stream, c1w, wpkc1);
  hipLaunchKernelGGL((k_pack_w<1, 6, 96>), dim3((3 * 6 * 512 + 255) / 256), b256, 0, stream, p2w, wpkp2);
  hipLaunchKernelGGL(k_pack_dwt, dim3((25 * Cc + 255) / 256), b256, 0, stream, d0w, dwt0, 25);
  hipLaunchKernelGGL(k_pack_dwt, dim3((49 * Cc + 255) / 256), b256, 0, stream, d1w, dwt1, 49);

  hipLaunchKernelGGL(k_ln, dim3(Nc / 256), b256, 0, stream, x, g1n, b1n, yln_n);
  hipLaunchKernelGGL((k_pwg<1, 2, 60>), dim3(Nc / 32), b256, 0, stream, yln_n, wpkp1, p1b, u_pad);
  // v8 convs: LDS double-buffered tap pipeline; SPLIT=2 each.
  hipLaunchKernelGGL((k_conv_lds<5, 1, 4, 50, 2, 60, 64, 2>), dim3(Nc / 128, 2), b256, 0, stream,
                     u_pad, wpk0, o0b, off0t);
  hipLaunchKernelGGL((k_meta<5, 1, 2, 64, 2>), dim3((Nc * 25 + 255) / 256), b256, 0, stream,
                     off0t, metaM0);
  hipLaunchKernelGGL((k_deform3<5, 2, 60, 9, 74>), dim3(Nc * 24 / 256), b256, 0, stream,
                     u_pad, metaM0, dwt0, d0b, a0_pad);
  hipLaunchKernelGGL((k_conv_lds<7, 3, 7, 98, 9, 74, 112, 2>), dim3(Nc / 128, 2), b256, 0, stream,
                     a0_pad, wpk1, o1b, off1t);
  hipLaunchKernelGGL((k_meta<7, 3, 9, 112, 2>), dim3((Nc * 49 + 255) / 256), b256, 0, stream,
                     off1t, metaM1);
  hipLaunchKernelGGL((k_deform3<7, 9, 74, 0, 56>), dim3(Nc * 24 / 256), b256, 0, stream,
                     a0_pad, metaM1, dwt1, d1b, a1_n);
  hipLaunchKernelGGL((k_pwg<0, 0, 56>), dim3(Nc / 32), b256, 0, stream, a1_n, wpkc1, c1b, A_n);
  hipLaunchKernelGGL((k_comb<2, 60>), dim3(Nc / 32), b256, 0, stream,
                     u_pad, A_n, wpkp2, p2b, yln_n, ls1, x, out, y2_n);
  hipLaunchKernelGGL(k_mlp1, dim3(Nc / 256), b256, 0, stream, y2_n, g2n, b2n, f1w, f1b, z4);
  hipLaunchKernelGGL(k_mlp_dw, dim3(Nc * 4 / 256), b256, 0, stream, z4, dww, dwb, z4b);
  hipLaunchKernelGGL(k_mlp2, dim3(Nc / 256), b256, 0, stream, z4b, f2w, f2b, ls2, out);
}

// Round 15
// 223.509 us; speedup vs baseline: 1.1992x; 1.1992x over previous
//
#include <hip/hip_runtime.h>
#include <math.h>

namespace {

constexpr int Bc = 4, Cc = 96, Hc = 56, Wc = 56;
constexpr int HWc = Hc * Wc;       // 3136
constexpr int Nc  = Bc * HWc;      // 12544
constexpr float EPSc = 1e-5f;

typedef __attribute__((ext_vector_type(8))) short bf16x8;
typedef __attribute__((ext_vector_type(4))) float f32x4;

__device__ __forceinline__ unsigned short f2bf(float f) {
  union { float f; unsigned u; } x; x.f = f;
  unsigned r = x.u + 0x7fffu + ((x.u >> 16) & 1u);
  return (unsigned short)(r >> 16);
}
__device__ __forceinline__ float bf2f(unsigned short u) {
  union { unsigned u; float f; } x; x.u = (unsigned)u << 16; return x.f;
}
__device__ __forceinline__ float gelu_exact(float x) {
  return 0.5f * x * (1.0f + erff(x * 0.7071067811865475f));
}

// ---------------- LayerNorm over channel dim -> bf16 NHWC ----------------
__global__ __launch_bounds__(256) void k_ln(const float* __restrict__ x,
                                            const float* __restrict__ g,
                                            const float* __restrict__ b,
                                            unsigned short* __restrict__ outN) {
  int pos = blockIdx.x * 256 + threadIdx.x;
  int bb = pos / HWc, hw = pos % HWc;
  const float* xb = x + (size_t)bb * Cc * HWc + hw;
  float s = 0.f, s2 = 0.f;
  for (int c = 0; c < Cc; ++c) { float v = xb[c * HWc]; s += v; s2 += v * v; }
  float mu  = s * (1.f / Cc);
  float var = fmaxf(s2 * (1.f / Cc) - mu * mu, 0.f);
  float rs  = rsqrtf(var + EPSc);
  unsigned short* ob = outN + (size_t)pos * Cc;
  for (int q = 0; q < 12; ++q) {
    unsigned short t8[8];
#pragma unroll
    for (int j = 0; j < 8; ++j) {
      int c = q * 8 + j;
      t8[j] = f2bf((xb[c * HWc] - mu) * rs * g[c] + b[c]);
    }
    *reinterpret_cast<bf16x8*>(ob + q * 8) = *reinterpret_cast<const bf16x8*>(t8);
  }
}

// ---------------- weight pack: W[o][c][ky][kx] -> frag layout bf16 ----------------
template <int K_, int MTILES, int P>
__global__ __launch_bounds__(256) void k_pack_w(const float* __restrict__ wsrc,
                                                unsigned short* __restrict__ wpk) {
  constexpr int TOTAL = K_ * K_ * 3 * MTILES * 512;
  int idx = blockIdx.x * 256 + threadIdx.x;
  if (idx >= TOTAL) return;
  int j    = idx & 7;
  int lane = (idx >> 3) & 63;
  int t    = idx >> 9;             // (p*3+cc)*MTILES + mt
  int mt   = t % MTILES;
  int step = t / MTILES;
  int o = mt * 16 + (lane & 15);
  int k = step * 32 + ((lane >> 4) & 3) * 8 + j;
  int p = k / Cc, c = k % Cc;
  float v = 0.f;
  if (o < P) v = wsrc[(((size_t)o * Cc + c) * K_ + p / K_) * K_ + (p % K_)];
  wpk[idx] = f2bf(v);
}

// ---------------- depthwise weight transpose [C][KK] -> [KK][C] ----------------
__global__ __launch_bounds__(256) void k_pack_dwt(const float* __restrict__ dwsrc,
                                                  float* __restrict__ dwt, int KK) {
  int idx = blockIdx.x * 256 + threadIdx.x;
  if (idx >= KK * Cc) return;
  int p = idx / Cc, c = idx % Cc;
  dwt[idx] = dwsrc[c * KK + p];
}

// ---------------- pointwise 96x96 MFMA GEMM: bf16 NHWC in -> bf16 (padded) NHWC out ----------
template <int GELU, int PADP, int WP>
__global__ __launch_bounds__(256) void k_pwg(const unsigned short* __restrict__ inN,
                                             const unsigned short* __restrict__ wpk,
                                             const float* __restrict__ bq,
                                             unsigned short* __restrict__ outPad) {
  int lane = threadIdx.x & 63;
  int wv = threadIdx.x >> 6;
  int ng = wv & 1, mg = wv >> 1;
  int n = blockIdx.x * 32 + ng * 16 + (lane & 15);
  int ko = ((lane >> 4) & 3) * 8;
  const unsigned short* ib = inN + (size_t)n * Cc + ko;
  const unsigned short* wl = wpk + (size_t)lane * 8;
  f32x4 acc[3];
#pragma unroll
  for (int m = 0; m < 3; ++m) acc[m] = (f32x4){0.f, 0.f, 0.f, 0.f};
#pragma unroll
  for (int ks = 0; ks < 3; ++ks) {
    bf16x8 bf = *reinterpret_cast<const bf16x8*>(ib + ks * 32);
#pragma unroll
    for (int m = 0; m < 3; ++m) {
      bf16x8 af = *reinterpret_cast<const bf16x8*>(wl + (size_t)(ks * 6 + mg * 3 + m) * 512);
      acc[m] = __builtin_amdgcn_mfma_f32_16x16x32_bf16(af, bf, acc[m], 0, 0, 0);
    }
  }
  int bb = n / HWc, hw = n % HWc;
  int h = hw / Wc, w = hw % Wc;
  unsigned short* ob = outPad + (((size_t)bb * (Hc + 2 * PADP) + h + PADP) * WP + w + PADP) * Cc;
  int orow = ((lane >> 4) & 3) * 4;
#pragma unroll
  for (int m = 0; m < 3; ++m) {
    int o0 = (mg * 3 + m) * 16 + orow;
    float4 bv = *reinterpret_cast<const float4*>(bq + o0);
    unsigned short t4[4];
#pragma unroll
    for (int j = 0; j < 4; ++j) {
      float r = acc[m][j] + ((const float*)&bv)[j];
      if (GELU) r = gelu_exact(r);
      t4[j] = f2bf(r);
    }
    *reinterpret_cast<uint2*>(ob + o0) = *reinterpret_cast<const uint2*>(t4);
  }
}

// ---------------- combine: GEMM p2w over (u*A) + yln + ls1, residual out, y2 NHWC ----------
template <int UPADP, int UWP>
__global__ __launch_bounds__(256) void k_comb(const unsigned short* __restrict__ uPad,
                                              const unsigned short* __restrict__ An,
                                              const unsigned short* __restrict__ wpk,
                                              const float* __restrict__ bq,
                                              const unsigned short* __restrict__ ylnN,
                                              const float* __restrict__ ls1q,
                                              const float* __restrict__ x,
                                              float* __restrict__ out,
                                              unsigned short* __restrict__ y2N) {
  int lane = threadIdx.x & 63;
  int wv = threadIdx.x >> 6;
  int ng = wv & 1, mg = wv >> 1;
  int n = blockIdx.x * 32 + ng * 16 + (lane & 15);
  int ko = ((lane >> 4) & 3) * 8;
  int bb = n / HWc, hw = n % HWc;
  int h = hw / Wc, w = hw % Wc;
  const unsigned short* ub = uPad + (((size_t)bb * (Hc + 2 * UPADP) + h + UPADP) * UWP + w + UPADP) * Cc + ko;
  const unsigned short* ab = An + (size_t)n * Cc + ko;
  const unsigned short* wl = wpk + (size_t)lane * 8;
  f32x4 acc[3];
#pragma unroll
  for (int m = 0; m < 3; ++m) acc[m] = (f32x4){0.f, 0.f, 0.f, 0.f};
#pragma unroll
  for (int ks = 0; ks < 3; ++ks) {
    bf16x8 uv = *reinterpret_cast<const bf16x8*>(ub + ks * 32);
    bf16x8 av = *reinterpret_cast<const bf16x8*>(ab + ks * 32);
    union { bf16x8 v; unsigned short s[8]; } uu, aa, gg;
    uu.v = uv; aa.v = av;
#pragma unroll
    for (int j = 0; j < 8; ++j) gg.s[j] = f2bf(bf2f(uu.s[j]) * bf2f(aa.s[j]));
#pragma unroll
    for (int m = 0; m < 3; ++m) {
      bf16x8 af = *reinterpret_cast<const bf16x8*>(wl + (size_t)(ks * 6 + mg * 3 + m) * 512);
      acc[m] = __builtin_amdgcn_mfma_f32_16x16x32_bf16(af, gg.v, acc[m], 0, 0, 0);
    }
  }
  int orow = ((lane >> 4) & 3) * 4;
  const float* xb = x + (size_t)bb * Cc * HWc + hw;
  float* ob = out + (size_t)bb * Cc * HWc + hw;
#pragma unroll
  for (int m = 0; m < 3; ++m) {
    int o0 = (mg * 3 + m) * 16 + orow;
    float4 bv = *reinterpret_cast<const float4*>(bq + o0);
    float4 lv = *reinterpret_cast<const float4*>(ls1q + o0);
    uint2 yl = *reinterpret_cast<const uint2*>(ylnN + (size_t)n * Cc + o0);
    unsigned short yl4[4];
    *reinterpret_cast<uint2*>(yl4) = yl;
    unsigned short t4[4];
#pragma unroll
    for (int j = 0; j < 4; ++j) {
      float t = acc[m][j] + ((const float*)&bv)[j] + bf2f(yl4[j]);
      float y2 = ((const float*)&lv)[j] * t;
      t4[j] = f2bf(y2);
      ob[(size_t)(o0 + j) * HWc] = xb[(size_t)(o0 + j) * HWc] + y2;
    }
    *reinterpret_cast<uint2*>(y2N + (size_t)n * Cc + o0) = *reinterpret_cast<const uint2*>(t4);
  }
}

// ---------------- implicit-GEMM MFMA conv v4: NT=2, in-block m-split ----------------
template <int K_, int DIL_, int MTILES, int MT, int P, int PADP, int WP, int PSTR>
__global__ __launch_bounds__(256) void k_conv_mfma(const unsigned short* __restrict__ inp,
                                                   const unsigned short* __restrict__ wpk,
                                                   const float* __restrict__ bq,
                                                   float* __restrict__ dstT) {
  constexpr int KK = K_ * K_;
  constexpr int HP = Hc + 2 * PADP;
  constexpr int NBLK = Nc / 32;                  // 392
  int lane = threadIdx.x & 63;
  int wv = threadIdx.x >> 6;
  int bid = blockIdx.x;
  int ntile = (bid & 7) * (NBLK / 8) + (bid >> 3);   // XCD swizzle (392 % 8 == 0)
  int n0 = ntile * 32 + (lane & 15);
  int n1 = n0 + 16;
  int b0 = n0 / HWc, hw0 = n0 % HWc, h0 = hw0 / Wc, w0 = hw0 % Wc;
  int b1 = n1 / HWc, hw1 = n1 % HWc, h1 = hw1 / Wc, w1 = hw1 % Wc;
  int co = ((lane >> 4) & 3) * 8;
  const unsigned short* ib0 = inp + ((size_t)b0 * HP * WP + (size_t)h0 * WP + w0) * Cc + co;
  const unsigned short* ib1 = inp + ((size_t)b1 * HP * WP + (size_t)h1 * WP + w1) * Cc + co;
  const unsigned short* wl = wpk + (size_t)lane * 8;
  int mt0 = wv * MT;
  int mtc[MT];
#pragma unroll
  for (int i = 0; i < MT; ++i) mtc[i] = min(mt0 + i, MTILES - 1);

  f32x4 acc[MT][2];
#pragma unroll
  for (int i = 0; i < MT; ++i) {
    acc[i][0] = (f32x4){0.f, 0.f, 0.f, 0.f};
    acc[i][1] = (f32x4){0.f, 0.f, 0.f, 0.f};
  }

  bf16x8 Bb[3][2], Aa[MT][3];
#pragma unroll
  for (int cc = 0; cc < 3; ++cc) {
    Bb[cc][0] = *reinterpret_cast<const bf16x8*>(ib0 + cc * 32);
    Bb[cc][1] = *reinterpret_cast<const bf16x8*>(ib1 + cc * 32);
#pragma unroll
    for (int i = 0; i < MT; ++i)
      Aa[i][cc] = *reinterpret_cast<const bf16x8*>(wl + ((size_t)cc * MTILES + mtc[i]) * 512);
  }

#pragma unroll 2
  for (int p = 0; p < KK; ++p) {
    int pn = (p + 1 < KK) ? p + 1 : p;
    size_t toff = (size_t)((pn / K_) * DIL_ * WP + (pn % K_) * DIL_) * Cc;
    const unsigned short* sp0 = ib0 + toff;
    const unsigned short* sp1 = ib1 + toff;
    bf16x8 Bn[3][2], An[MT][3];
#pragma unroll
    for (int cc = 0; cc < 3; ++cc) {
      Bn[cc][0] = *reinterpret_cast<const bf16x8*>(sp0 + cc * 32);
      Bn[cc][1] = *reinterpret_cast<const bf16x8*>(sp1 + cc * 32);
#pragma unroll
      for (int i = 0; i < MT; ++i)
        An[i][cc] = *reinterpret_cast<const bf16x8*>(wl + ((size_t)(pn * 3 + cc) * MTILES + mtc[i]) * 512);
    }
#pragma unroll
    for (int cc = 0; cc < 3; ++cc)
#pragma unroll
      for (int i = 0; i < MT; ++i) {
        acc[i][0] = __builtin_amdgcn_mfma_f32_16x16x32_bf16(Aa[i][cc], Bb[cc][0], acc[i][0], 0, 0, 0);
        acc[i][1] = __builtin_amdgcn_mfma_f32_16x16x32_bf16(Aa[i][cc], Bb[cc][1], acc[i][1], 0, 0, 0);
      }
#pragma unroll
    for (int cc = 0; cc < 3; ++cc) {
      Bb[cc][0] = Bn[cc][0];
      Bb[cc][1] = Bn[cc][1];
#pragma unroll
      for (int i = 0; i < MT; ++i) Aa[i][cc] = An[i][cc];
    }
  }

  int orow = ((lane >> 4) & 3) * 4;
#pragma unroll
  for (int i = 0; i < MT; ++i) {
    int mt = mt0 + i;
    if (mt >= MTILES) break;
#pragma unroll
    for (int nt = 0; nt < 2; ++nt) {
      float4 st;
#pragma unroll
      for (int j = 0; j < 4; ++j) {
        int o = mt * 16 + orow + j;
        float bias = (o < P) ? bq[o] : 0.f;
        ((float*)&st)[j] = acc[i][nt][j] + bias;
      }
      int n = nt ? n1 : n0;
      *reinterpret_cast<float4*>(dstT + (size_t)n * PSTR + mt * 16 + orow) = st;
    }
  }
}

// ---------------- deformable depthwise sampling (bf16 padded NHWC src) ----------------
template <int K_, int DIL_, int PAD_, int IPADP, int IWP, int OPADP, int OWP, int PSTR>
__global__ __launch_bounds__(256) void k_deform(const unsigned short* __restrict__ srcT,
                                                const float* __restrict__ offT,
                                                const float* __restrict__ dwt,
                                                const float* __restrict__ dbq,
                                                float* __restrict__ dst,
                                                unsigned short* __restrict__ dstPad) {
  constexpr int KK = K_ * K_;
  constexpr int KK4 = KK & ~3;
  constexpr int IHP = Hc + 2 * IPADP;
  int tid = blockIdx.x * 256 + threadIdx.x;      // N*24 threads
  int cg = tid % 24;
  int pos = tid / 24;
  int c = cg * 4;
  int bb = pos / HWc, hw = pos % HWc;
  int h = hw / Wc, w = hw % Wc;
  const unsigned short* sb = srcT + (size_t)bb * IHP * IWP * Cc + c;
  const float* ob = offT + (size_t)pos * PSTR;
  float ax = 0.f, ay = 0.f, az = 0.f, aw = 0.f;

  for (int pg = 0; pg < KK4; pg += 4) {
    float4 o01 = *reinterpret_cast<const float4*>(ob + 2 * pg);
    float4 o23 = *reinterpret_cast<const float4*>(ob + 2 * pg + 4);
    float oyv[4] = {o01.x, o01.z, o23.x, o23.z};
    float oxv[4] = {o01.y, o01.w, o23.y, o23.w};
    uint2 v[4][4];
    float wt[4][4];
#pragma unroll
    for (int i = 0; i < 4; ++i) {
      int p = pg + i;
      float py = (float)(h + (p / K_) * DIL_ - PAD_) + oyv[i];
      float px = (float)(w + (p % K_) * DIL_ - PAD_) + oxv[i];
      float y0f = floorf(py), x0f = floorf(px);
      float wy = py - y0f, wx = px - x0f;
      int y0 = (int)y0f, x0 = (int)x0f;
#pragma unroll
      for (int dy = 0; dy < 2; ++dy) {
        int yi = y0 + dy;
        bool yv = (unsigned)yi < (unsigned)Hc;
        int yc = min(max(yi, 0), Hc - 1);
        float wyv = dy ? wy : 1.f - wy;
#pragma unroll
        for (int dx = 0; dx < 2; ++dx) {
          int xi = x0 + dx;
          bool xv = (unsigned)xi < (unsigned)Wc;
          int xc = min(max(xi, 0), Wc - 1);
          wt[i][dy * 2 + dx] = (yv && xv) ? wyv * (dx ? wx : 1.f - wx) : 0.f;
          v[i][dy * 2 + dx] = *reinterpret_cast<const uint2*>(
              sb + ((size_t)(yc + IPADP) * IWP + (xc + IPADP)) * Cc);
        }
      }
    }
#pragma unroll
    for (int i = 0; i < 4; ++i) {
      int p = pg + i;
      float4 d = *reinterpret_cast<const float4*>(dwt + (size_t)p * Cc + c);
      float sx = 0.f, sy = 0.f, sz = 0.f, sw = 0.f;
#pragma unroll
      for (int q = 0; q < 4; ++q) {
        float wq_ = wt[i][q];
        sx += wq_ * bf2f((unsigned short)(v[i][q].x & 0xffffu));
        sy += wq_ * bf2f((unsigned short)(v[i][q].x >> 16));
        sz += wq_ * bf2f((unsigned short)(v[i][q].y & 0xffffu));
        sw += wq_ * bf2f((unsigned short)(v[i][q].y >> 16));
      }
      ax += sx * d.x; ay += sy * d.y; az += sz * d.z; aw += sw * d.w;
    }
  }
  // tail tap (KK % 4 == 1 for K=5,7)
  {
    int p = KK - 1;
    float oy = ob[2 * p], ox = ob[2 * p + 1];
    float py = (float)(h + (p / K_) * DIL_ - PAD_) + oy;
    float px = (float)(w + (p % K_) * DIL_ - PAD_) + ox;
    float y0f = floorf(py), x0f = floorf(px);
    float wy = py - y0f, wx = px - x0f;
    int y0 = (int)y0f, x0 = (int)x0f;
    uint2 v[4]; float wt[4];
#pragma unroll
    for (int dy = 0; dy < 2; ++dy) {
      int yi = y0 + dy;
      bool yv = (unsigned)yi < (unsigned)Hc;
      int yc = min(max(yi, 0), Hc - 1);
      float wyv = dy ? wy : 1.f - wy;
#pragma unroll
      for (int dx = 0; dx < 2; ++dx) {
        int xi = x0 + dx;
        bool xv = (unsigned)xi < (unsigned)Wc;
        int xc = min(max(xi, 0), Wc - 1);
        wt[dy * 2 + dx] = (yv && xv) ? wyv * (dx ? wx : 1.f - wx) : 0.f;
        v[dy * 2 + dx] = *reinterpret_cast<const uint2*>(
            sb + ((size_t)(yc + IPADP) * IWP + (xc + IPADP)) * Cc);
      }
    }
    float4 d = *reinterpret_cast<const float4*>(dwt + (size_t)p * Cc + c);
    float sx = 0.f, sy = 0.f, sz = 0.f, sw = 0.f;
#pragma unroll
    for (int q = 0; q < 4; ++q) {
      sx += wt[q] * bf2f((unsigned short)(v[q].x & 0xffffu));
      sy += wt[q] * bf2f((unsigned short)(v[q].x >> 16));
      sz += wt[q] * bf2f((unsigned short)(v[q].y & 0xffffu));
      sw += wt[q] * bf2f((unsigned short)(v[q].y >> 16));
    }
    ax += sx * d.x; ay += sy * d.y; az += sz * d.z; aw += sw * d.w;
  }

  ax += dbq[c]; ay += dbq[c + 1]; az += dbq[c + 2]; aw += dbq[c + 3];
  if (dst) {
    float* d = dst + (size_t)bb * Cc * HWc + hw;
    d[(c + 0) * HWc] = ax; d[(c + 1) * HWc] = ay;
    d[(c + 2) * HWc] = az; d[(c + 3) * HWc] = aw;
  }
  if (dstPad) {
    unsigned short t4[4] = {f2bf(ax), f2bf(ay), f2bf(az), f2bf(aw)};
    unsigned short* tb = dstPad + (((size_t)bb * (Hc + 2 * OPADP) + h + OPADP) * OWP + w + OPADP) * Cc + c;
    *reinterpret_cast<uint2*>(tb) = *reinterpret_cast<const uint2*>(t4);
  }
}

// ---------------- MLP: LN2 + f1 (96->4), y2 in bf16 NHWC ----------------
__global__ __launch_bounds__(256) void k_mlp1(const unsigned short* __restrict__ y2N,
                                              const float* __restrict__ g,
                                              const float* __restrict__ b,
                                              const float* __restrict__ f1wq,
                                              const float* __restrict__ f1bq,
                                              float* __restrict__ z4) {
  int pos = blockIdx.x * 256 + threadIdx.x;
  int bb = pos / HWc, hw = pos % HWc;
  const unsigned short* yb = y2N + (size_t)pos * Cc;
  float vv[96];
  float s = 0.f, s2 = 0.f;
#pragma unroll
  for (int q = 0; q < 12; ++q) {
    bf16x8 t = *reinterpret_cast<const bf16x8*>(yb + q * 8);
    union { bf16x8 v; unsigned short s[8]; } u; u.v = t;
#pragma unroll
    for (int j = 0; j < 8; ++j) {
      float f = bf2f(u.s[j]);
      vv[q * 8 + j] = f; s += f; s2 += f * f;
    }
  }
  float mu  = s * (1.f / Cc);
  float var = fmaxf(s2 * (1.f / Cc) - mu * mu, 0.f);
  float rs  = rsqrtf(var + EPSc);
  float a0 = 0.f, a1 = 0.f, a2 = 0.f, a3 = 0.f;
#pragma unroll
  for (int c = 0; c < 96; ++c) {
    float t = (vv[c] - mu) * rs * g[c] + b[c];
    a0 += t * f1wq[0 * Cc + c];
    a1 += t * f1wq[1 * Cc + c];
    a2 += t * f1wq[2 * Cc + c];
    a3 += t * f1wq[3 * Cc + c];
  }
  float* zb = z4 + (size_t)bb * 4 * HWc + hw;
  zb[0 * HWc] = a0 + f1bq[0];
  zb[1 * HWc] = a1 + f1bq[1];
  zb[2 * HWc] = a2 + f1bq[2];
  zb[3 * HWc] = a3 + f1bq[3];
}

// ---------------- MLP: depthwise 3x3 (4 ch) + GELU ----------------
__global__ __launch_bounds__(256) void k_mlp_dw(const float* __restrict__ z4,
                                                const float* __restrict__ dwwq,
                                                const float* __restrict__ dwbq,
                                                float* __restrict__ z4b) {
  int tid = blockIdx.x * 256 + threadIdx.x;
  int hw = tid % HWc;
  int bj = tid / HWc;
  int j = bj % 4;
  int h = hw / Wc, w = hw % Wc;
  const float* zb = z4 + (size_t)bj * HWc;
  float s = 0.f;
#pragma unroll
  for (int ky = 0; ky < 3; ++ky) {
    int y = h + ky - 1;
    if ((unsigned)y >= (unsigned)Hc) continue;
#pragma unroll
    for (int kx = 0; kx < 3; ++kx) {
      int x = w + kx - 1;
      if ((unsigned)x >= (unsigned)Wc) continue;
      s += zb[y * Wc + x] * dwwq[j * 9 + ky * 3 + kx];
    }
  }
  z4b[tid] = gelu_exact(s + dwbq[j]);
}

// ---------------- MLP: f2 (4->96) + ls2 + residual add into out ----------------
__global__ __launch_bounds__(256) void k_mlp2(const float* __restrict__ z4b,
                                              const float* __restrict__ f2wq,
                                              const float* __restrict__ f2bq,
                                              const float* __restrict__ ls2q,
                                              float* __restrict__ out) {
  int pos = blockIdx.x * 256 + threadIdx.x;
  int bb = pos / HWc, hw = pos % HWc;
  const float* zb = z4b + (size_t)bb * 4 * HWc + hw;
  float z0 = zb[0 * HWc], z1 = zb[1 * HWc], z2 = zb[2 * HWc], z3 = zb[3 * HWc];
  float* ob = out + (size_t)bb * Cc * HWc + hw;
  for (int o = 0; o < Cc; ++o) {
    float s = f2bq[o] + z0 * f2wq[o * 4 + 0] + z1 * f2wq[o * 4 + 1]
                      + z2 * f2wq[o * 4 + 2] + z3 * f2wq[o * 4 + 3];
    ob[o * HWc] += ls2q[o] * s;
  }
}

}  // namespace

extern "C" void kernel_launch(void* const* d_in, const int* in_sizes, int n_in,
                              void* d_out, int out_size, void* d_ws, size_t ws_size,
                              hipStream_t stream) {
  (void)in_sizes; (void)n_in; (void)out_size; (void)ws_size;
  const float* x   = (const float*)d_in[0];
  const float* g1n = (const float*)d_in[1];
  const float* b1n = (const float*)d_in[2];
  const float* p1w = (const float*)d_in[3];
  const float* p1b = (const float*)d_in[4];
  const float* o0w = (const float*)d_in[5];
  const float* o0b = (const float*)d_in[6];
  const float* d0w = (const float*)d_in[7];
  const float* d0b = (const float*)d_in[8];
  const float* o1w = (const float*)d_in[9];
  const float* o1b = (const float*)d_in[10];
  const float* d1w = (const float*)d_in[11];
  const float* d1b = (const float*)d_in[12];
  const float* c1w = (const float*)d_in[13];
  const float* c1b = (const float*)d_in[14];
  const float* p2w = (const float*)d_in[15];
  const float* p2b = (const float*)d_in[16];
  const float* ls1 = (const float*)d_in[17];
  const float* g2n = (const float*)d_in[18];
  const float* b2n = (const float*)d_in[19];
  const float* f1w = (const float*)d_in[20];
  const float* f1b = (const float*)d_in[21];
  const float* dww = (const float*)d_in[22];
  const float* dwb = (const float*)d_in[23];
  const float* f2w = (const float*)d_in[24];
  const float* f2b = (const float*)d_in[25];
  const float* ls2 = (const float*)d_in[26];
  float* out = (float*)d_out;
  float* ws  = (float*)d_ws;

  float* off0t = ws;                                  size_t o_ = (size_t)Nc * 64;
  float* off1t = ws + o_;                             o_ += (size_t)Nc * 112;
  float* z4    = ws + o_;                             o_ += (size_t)Bc * 4 * HWc;
  float* z4b   = ws + o_;                             o_ += (size_t)Bc * 4 * HWc;
  float* dwt0  = ws + o_;                             o_ += 25 * Cc;
  float* dwt1  = ws + o_;                             o_ += 49 * Cc;
  unsigned short* yln_n  = (unsigned short*)(ws + o_); o_ += (size_t)Nc * Cc / 2;
  unsigned short* a1_n   = (unsigned short*)(ws + o_); o_ += (size_t)Nc * Cc / 2;
  unsigned short* A_n    = (unsigned short*)(ws + o_); o_ += (size_t)Nc * Cc / 2;
  unsigned short* y2_n   = (unsigned short*)(ws + o_); o_ += (size_t)Nc * Cc / 2;
  unsigned short* u_pad  = (unsigned short*)(ws + o_); o_ += (size_t)Bc * 60 * 60 * Cc / 2;
  unsigned short* a0_pad = (unsigned short*)(ws + o_); o_ += (size_t)Bc * 74 * 74 * Cc / 2;
  unsigned short* wpk0   = (unsigned short*)(ws + o_); o_ += (size_t)25 * 3 * 4 * 512 / 2;
  unsigned short* wpk1   = (unsigned short*)(ws + o_); o_ += (size_t)49 * 3 * 7 * 512 / 2;
  unsigned short* wpkp1  = (unsigned short*)(ws + o_); o_ += (size_t)3 * 6 * 512 / 2;
  unsigned short* wpkc1  = (unsigned short*)(ws + o_); o_ += (size_t)3 * 6 * 512 / 2;
  unsigned short* wpkp2  = (unsigned short*)(ws + o_); o_ += (size_t)3 * 6 * 512 / 2;

  dim3 b256(256, 1, 1);

  hipMemsetAsync(u_pad, 0, (size_t)Bc * 60 * 60 * Cc * sizeof(unsigned short), stream);
  hipMemsetAsync(a0_pad, 0, (size_t)Bc * 74 * 74 * Cc * sizeof(unsigned short), stream);
  hipLaunchKernelGGL((k_pack_w<5, 4, 50>), dim3((25 * 3 * 4 * 512 + 255) / 256), b256, 0, stream, o0w, wpk0);
  hipLaunchKernelGGL((k_pack_w<7, 7, 98>), dim3((49 * 3 * 7 * 512 + 255) / 256), b256, 0, stream, o1w, wpk1);
  hipLaunchKernelGGL((k_pack_w<1, 6, 96>), dim3((3 * 6 * 512 + 255) / 256), b256, 0, stream, p1w, wpkp1);
  hipLaunchKernelGGL((k_pack_w<1, 6, 96>), dim3((3 * 6 * 512 + 255) / 256), b256, 0, stream, c1w, wpkc1);
  hipLaunchKernelGGL((k_pack_w<1, 6, 96>), dim3((3 * 6 * 512 + 255) / 256), b256, 0, stream, p2w, wpkp2);
  hipLaunchKernelGGL(k_pack_dwt, dim3((25 * Cc + 255) / 256), b256, 0, stream, d0w, dwt0, 25);
  hipLaunchKernelGGL(k_pack_dwt, dim3((49 * Cc + 255) / 256), b256, 0, stream, d1w, dwt1, 49);

  hipLaunchKernelGGL(k_ln, dim3(Nc / 256), b256, 0, stream, x, g1n, b1n, yln_n);
  hipLaunchKernelGGL((k_pwg<1, 2, 60>), dim3(Nc / 32), b256, 0, stream, yln_n, wpkp1, p1b, u_pad);
  hipLaunchKernelGGL((k_conv_mfma<5, 1, 4, 1, 50, 2, 60, 64>), dim3(Nc / 32), b256, 0, stream,
                     u_pad, wpk0, o0b, off0t);
  hipLaunchKernelGGL((k_deform<5, 1, 2, 2, 60, 9, 74, 64>), dim3(Nc * 24 / 256), b256, 0, stream,
                     u_pad, off0t, dwt0, d0b, (float*)nullptr, a0_pad);
  hipLaunchKernelGGL((k_conv_mfma<7, 3, 7, 2, 98, 9, 74, 112>), dim3(Nc / 32), b256, 0, stream,
                     a0_pad, wpk1, o1b, off1t);
  hipLaunchKernelGGL((k_deform<7, 3, 9, 9, 74, 0, 56, 112>), dim3(Nc * 24 / 256), b256, 0, stream,
                     a0_pad, off1t, dwt1, d1b, (float*)nullptr, a1_n);
  hipLaunchKernelGGL((k_pwg<0, 0, 56>), dim3(Nc / 32), b256, 0, stream, a1_n, wpkc1, c1b, A_n);
  hipLaunchKernelGGL((k_comb<2, 60>), dim3(Nc / 32), b256, 0, stream,
                     u_pad, A_n, wpkp2, p2b, yln_n, ls1, x, out, y2_n);
  hipLaunchKernelGGL(k_mlp1, dim3(Nc / 256), b256, 0, stream, y2_n, g2n, b2n, f1w, f1b, z4);
  hipLaunchKernelGGL(k_mlp_dw, dim3(Nc * 4 / 256), b256, 0, stream, z4, dww, dwb, z4b);
  hipLaunchKernelGGL(k_mlp2, dim3(Nc / 256), b256, 0, stream, z4b, f2w, f2b, ls2, out);
}

// Round 16
// 222.832 us; speedup vs baseline: 1.2028x; 1.0030x over previous
//
#include <hip/hip_runtime.h>
#include <math.h>

namespace {

constexpr int Bc = 4, Cc = 96, Hc = 56, Wc = 56;
constexpr int HWc = Hc * Wc;       // 3136
constexpr int Nc  = Bc * HWc;      // 12544
constexpr float EPSc = 1e-5f;

typedef __attribute__((ext_vector_type(8))) short bf16x8;
typedef __attribute__((ext_vector_type(4))) float f32x4;

__device__ __forceinline__ unsigned short f2bf(float f) {
  union { float f; unsigned u; } x; x.f = f;
  unsigned r = x.u + 0x7fffu + ((x.u >> 16) & 1u);
  return (unsigned short)(r >> 16);
}
__device__ __forceinline__ float bf2f(unsigned short u) {
  union { unsigned u; float f; } x; x.u = (unsigned)u << 16; return x.f;
}
__device__ __forceinline__ float gelu_exact(float x) {
  return 0.5f * x * (1.0f + erff(x * 0.7071067811865475f));
}

// ---------------- LayerNorm over channel dim -> bf16 NHWC ----------------
__global__ __launch_bounds__(256) void k_ln(const float* __restrict__ x,
                                            const float* __restrict__ g,
                                            const float* __restrict__ b,
                                            unsigned short* __restrict__ outN) {
  int pos = blockIdx.x * 256 + threadIdx.x;
  int bb = pos / HWc, hw = pos % HWc;
  const float* xb = x + (size_t)bb * Cc * HWc + hw;
  float s = 0.f, s2 = 0.f;
  for (int c = 0; c < Cc; ++c) { float v = xb[c * HWc]; s += v; s2 += v * v; }
  float mu  = s * (1.f / Cc);
  float var = fmaxf(s2 * (1.f / Cc) - mu * mu, 0.f);
  float rs  = rsqrtf(var + EPSc);
  unsigned short* ob = outN + (size_t)pos * Cc;
  for (int q = 0; q < 12; ++q) {
    unsigned short t8[8];
#pragma unroll
    for (int j = 0; j < 8; ++j) {
      int c = q * 8 + j;
      t8[j] = f2bf((xb[c * HWc] - mu) * rs * g[c] + b[c]);
    }
    *reinterpret_cast<bf16x8*>(ob + q * 8) = *reinterpret_cast<const bf16x8*>(t8);
  }
}

// ---------------- weight pack: W[o][c][ky][kx] -> frag layout bf16 ----------------
template <int K_, int MTILES, int P>
__global__ __launch_bounds__(256) void k_pack_w(const float* __restrict__ wsrc,
                                                unsigned short* __restrict__ wpk) {
  constexpr int TOTAL = K_ * K_ * 3 * MTILES * 512;
  int idx = blockIdx.x * 256 + threadIdx.x;
  if (idx >= TOTAL) return;
  int j    = idx & 7;
  int lane = (idx >> 3) & 63;
  int t    = idx >> 9;             // (p*3+cc)*MTILES + mt
  int mt   = t % MTILES;
  int step = t / MTILES;
  int o = mt * 16 + (lane & 15);
  int k = step * 32 + ((lane >> 4) & 3) * 8 + j;
  int p = k / Cc, c = k % Cc;
  float v = 0.f;
  if (o < P) v = wsrc[(((size_t)o * Cc + c) * K_ + p / K_) * K_ + (p % K_)];
  wpk[idx] = f2bf(v);
}

// ---------------- depthwise weight transpose [C][KK] -> [KK][C] ----------------
__global__ __launch_bounds__(256) void k_pack_dwt(const float* __restrict__ dwsrc,
                                                  float* __restrict__ dwt, int KK) {
  int idx = blockIdx.x * 256 + threadIdx.x;
  if (idx >= KK * Cc) return;
  int p = idx / Cc, c = idx % Cc;
  dwt[idx] = dwsrc[c * KK + p];
}

// ---------------- pointwise 96x96 MFMA GEMM: bf16 NHWC in -> bf16 (padded) NHWC out ----------
template <int GELU, int PADP, int WP>
__global__ __launch_bounds__(256) void k_pwg(const unsigned short* __restrict__ inN,
                                             const unsigned short* __restrict__ wpk,
                                             const float* __restrict__ bq,
                                             unsigned short* __restrict__ outPad) {
  int lane = threadIdx.x & 63;
  int wv = threadIdx.x >> 6;
  int ng = wv & 1, mg = wv >> 1;
  int n = blockIdx.x * 32 + ng * 16 + (lane & 15);
  int ko = ((lane >> 4) & 3) * 8;
  const unsigned short* ib = inN + (size_t)n * Cc + ko;
  const unsigned short* wl = wpk + (size_t)lane * 8;
  f32x4 acc[3];
#pragma unroll
  for (int m = 0; m < 3; ++m) acc[m] = (f32x4){0.f, 0.f, 0.f, 0.f};
#pragma unroll
  for (int ks = 0; ks < 3; ++ks) {
    bf16x8 bf = *reinterpret_cast<const bf16x8*>(ib + ks * 32);
#pragma unroll
    for (int m = 0; m < 3; ++m) {
      bf16x8 af = *reinterpret_cast<const bf16x8*>(wl + (size_t)(ks * 6 + mg * 3 + m) * 512);
      acc[m] = __builtin_amdgcn_mfma_f32_16x16x32_bf16(af, bf, acc[m], 0, 0, 0);
    }
  }
  int bb = n / HWc, hw = n % HWc;
  int h = hw / Wc, w = hw % Wc;
  unsigned short* ob = outPad + (((size_t)bb * (Hc + 2 * PADP) + h + PADP) * WP + w + PADP) * Cc;
  int orow = ((lane >> 4) & 3) * 4;
#pragma unroll
  for (int m = 0; m < 3; ++m) {
    int o0 = (mg * 3 + m) * 16 + orow;
    float4 bv = *reinterpret_cast<const float4*>(bq + o0);
    unsigned short t4[4];
#pragma unroll
    for (int j = 0; j < 4; ++j) {
      float r = acc[m][j] + ((const float*)&bv)[j];
      if (GELU) r = gelu_exact(r);
      t4[j] = f2bf(r);
    }
    *reinterpret_cast<uint2*>(ob + o0) = *reinterpret_cast<const uint2*>(t4);
  }
}

// ---------------- combine: GEMM p2w over (u*A) + yln + ls1, residual out, y2 NHWC ----------
template <int UPADP, int UWP>
__global__ __launch_bounds__(256) void k_comb(const unsigned short* __restrict__ uPad,
                                              const unsigned short* __restrict__ An,
                                              const unsigned short* __restrict__ wpk,
                                              const float* __restrict__ bq,
                                              const unsigned short* __restrict__ ylnN,
                                              const float* __restrict__ ls1q,
                                              const float* __restrict__ x,
                                              float* __restrict__ out,
                                              unsigned short* __restrict__ y2N) {
  int lane = threadIdx.x & 63;
  int wv = threadIdx.x >> 6;
  int ng = wv & 1, mg = wv >> 1;
  int n = blockIdx.x * 32 + ng * 16 + (lane & 15);
  int ko = ((lane >> 4) & 3) * 8;
  int bb = n / HWc, hw = n % HWc;
  int h = hw / Wc, w = hw % Wc;
  const unsigned short* ub = uPad + (((size_t)bb * (Hc + 2 * UPADP) + h + UPADP) * UWP + w + UPADP) * Cc + ko;
  const unsigned short* ab = An + (size_t)n * Cc + ko;
  const unsigned short* wl = wpk + (size_t)lane * 8;
  f32x4 acc[3];
#pragma unroll
  for (int m = 0; m < 3; ++m) acc[m] = (f32x4){0.f, 0.f, 0.f, 0.f};
#pragma unroll
  for (int ks = 0; ks < 3; ++ks) {
    bf16x8 uv = *reinterpret_cast<const bf16x8*>(ub + ks * 32);
    bf16x8 av = *reinterpret_cast<const bf16x8*>(ab + ks * 32);
    union { bf16x8 v; unsigned short s[8]; } uu, aa, gg;
    uu.v = uv; aa.v = av;
#pragma unroll
    for (int j = 0; j < 8; ++j) gg.s[j] = f2bf(bf2f(uu.s[j]) * bf2f(aa.s[j]));
#pragma unroll
    for (int m = 0; m < 3; ++m) {
      bf16x8 af = *reinterpret_cast<const bf16x8*>(wl + (size_t)(ks * 6 + mg * 3 + m) * 512);
      acc[m] = __builtin_amdgcn_mfma_f32_16x16x32_bf16(af, gg.v, acc[m], 0, 0, 0);
    }
  }
  int orow = ((lane >> 4) & 3) * 4;
  const float* xb = x + (size_t)bb * Cc * HWc + hw;
  float* ob = out + (size_t)bb * Cc * HWc + hw;
#pragma unroll
  for (int m = 0; m < 3; ++m) {
    int o0 = (mg * 3 + m) * 16 + orow;
    float4 bv = *reinterpret_cast<const float4*>(bq + o0);
    float4 lv = *reinterpret_cast<const float4*>(ls1q + o0);
    uint2 yl = *reinterpret_cast<const uint2*>(ylnN + (size_t)n * Cc + o0);
    unsigned short yl4[4];
    *reinterpret_cast<uint2*>(yl4) = yl;
    unsigned short t4[4];
#pragma unroll
    for (int j = 0; j < 4; ++j) {
      float t = acc[m][j] + ((const float*)&bv)[j] + bf2f(yl4[j]);
      float y2 = ((const float*)&lv)[j] * t;
      t4[j] = f2bf(y2);
      ob[(size_t)(o0 + j) * HWc] = xb[(size_t)(o0 + j) * HWc] + y2;
    }
    *reinterpret_cast<uint2*>(y2N + (size_t)n * Cc + o0) = *reinterpret_cast<const uint2*>(t4);
  }
}

// ---------------- implicit-GEMM MFMA conv v9: NT=2, m-split + sched_barrier pipeline ----
template <int K_, int DIL_, int MTILES, int MT, int P, int PADP, int WP, int PSTR>
__global__ __launch_bounds__(256) void k_conv_mfma(const unsigned short* __restrict__ inp,
                                                   const unsigned short* __restrict__ wpk,
                                                   const float* __restrict__ bq,
                                                   float* __restrict__ dstT) {
  constexpr int KK = K_ * K_;
  constexpr int HP = Hc + 2 * PADP;
  constexpr int NBLK = Nc / 32;                  // 392
  int lane = threadIdx.x & 63;
  int wv = threadIdx.x >> 6;
  int bid = blockIdx.x;
  int ntile = (bid & 7) * (NBLK / 8) + (bid >> 3);   // XCD swizzle (392 % 8 == 0)
  int n0 = ntile * 32 + (lane & 15);
  int n1 = n0 + 16;
  int b0 = n0 / HWc, hw0 = n0 % HWc, h0 = hw0 / Wc, w0 = hw0 % Wc;
  int b1 = n1 / HWc, hw1 = n1 % HWc, h1 = hw1 / Wc, w1 = hw1 % Wc;
  int co = ((lane >> 4) & 3) * 8;
  const unsigned short* ib0 = inp + ((size_t)b0 * HP * WP + (size_t)h0 * WP + w0) * Cc + co;
  const unsigned short* ib1 = inp + ((size_t)b1 * HP * WP + (size_t)h1 * WP + w1) * Cc + co;
  const unsigned short* wl = wpk + (size_t)lane * 8;
  int mt0 = wv * MT;
  int mtc[MT];
#pragma unroll
  for (int i = 0; i < MT; ++i) mtc[i] = min(mt0 + i, MTILES - 1);

  f32x4 acc[MT][2];
#pragma unroll
  for (int i = 0; i < MT; ++i) {
    acc[i][0] = (f32x4){0.f, 0.f, 0.f, 0.f};
    acc[i][1] = (f32x4){0.f, 0.f, 0.f, 0.f};
  }

  bf16x8 B0[3][2], A0[MT][3], B1[3][2], A1[MT][3];

#define LOAD_TAP(Bb, Ab, pp)                                                          \
  {                                                                                   \
    size_t toff_ = (size_t)(((pp) / K_) * DIL_ * WP + ((pp) % K_) * DIL_) * Cc;       \
    _Pragma("unroll")                                                                 \
    for (int cc = 0; cc < 3; ++cc) {                                                  \
      Bb[cc][0] = *reinterpret_cast<const bf16x8*>(ib0 + toff_ + cc * 32);            \
      Bb[cc][1] = *reinterpret_cast<const bf16x8*>(ib1 + toff_ + cc * 32);            \
      _Pragma("unroll")                                                               \
      for (int i = 0; i < MT; ++i)                                                    \
        Ab[i][cc] = *reinterpret_cast<const bf16x8*>(                                 \
            wl + ((size_t)((pp) * 3 + cc) * MTILES + mtc[i]) * 512);                  \
    }                                                                                 \
  }
#define MFMA_TAP(Bb, Ab)                                                              \
  {                                                                                   \
    _Pragma("unroll")                                                                 \
    for (int cc = 0; cc < 3; ++cc)                                                    \
      _Pragma("unroll")                                                               \
      for (int i = 0; i < MT; ++i) {                                                  \
        acc[i][0] = __builtin_amdgcn_mfma_f32_16x16x32_bf16(Ab[i][cc], Bb[cc][0],     \
                                                            acc[i][0], 0, 0, 0);      \
        acc[i][1] = __builtin_amdgcn_mfma_f32_16x16x32_bf16(Ab[i][cc], Bb[cc][1],     \
                                                            acc[i][1], 0, 0, 0);      \
      }                                                                               \
  }

  LOAD_TAP(B0, A0, 0)
  LOAD_TAP(B1, A1, 1)
  int p = 0;
  for (; p + 2 < KK; p += 2) {
    MFMA_TAP(B0, A0)
    LOAD_TAP(B0, A0, p + 2)
    __builtin_amdgcn_sched_barrier(0);
    MFMA_TAP(B1, A1)
    if (p + 3 < KK) LOAD_TAP(B1, A1, p + 3)
    __builtin_amdgcn_sched_barrier(0);
  }
  // KK odd (25/49): taps ..., KK-2 in B1 (done), final tap KK-1 sits in B0
  MFMA_TAP(B0, A0)
#undef LOAD_TAP
#undef MFMA_TAP

  int orow = ((lane >> 4) & 3) * 4;
#pragma unroll
  for (int i = 0; i < MT; ++i) {
    int mt = mt0 + i;
    if (mt >= MTILES) break;
#pragma unroll
    for (int nt = 0; nt < 2; ++nt) {
      float4 st;
#pragma unroll
      for (int j = 0; j < 4; ++j) {
        int o = mt * 16 + orow + j;
        float bias = (o < P) ? bq[o] : 0.f;
        ((float*)&st)[j] = acc[i][nt][j] + bias;
      }
      int n = nt ? n1 : n0;
      *reinterpret_cast<float4*>(dstT + (size_t)n * PSTR + mt * 16 + orow) = st;
    }
  }
}

// ---------------- deformable depthwise sampling (bf16 padded NHWC src) ----------------
template <int K_, int DIL_, int PAD_, int IPADP, int IWP, int OPADP, int OWP, int PSTR>
__global__ __launch_bounds__(256) void k_deform(const unsigned short* __restrict__ srcT,
                                                const float* __restrict__ offT,
                                                const float* __restrict__ dwt,
                                                const float* __restrict__ dbq,
                                                float* __restrict__ dst,
                                                unsigned short* __restrict__ dstPad) {
  constexpr int KK = K_ * K_;
  constexpr int KK4 = KK & ~3;
  constexpr int IHP = Hc + 2 * IPADP;
  int tid = blockIdx.x * 256 + threadIdx.x;      // N*24 threads
  int cg = tid % 24;
  int pos = tid / 24;
  int c = cg * 4;
  int bb = pos / HWc, hw = pos % HWc;
  int h = hw / Wc, w = hw % Wc;
  const unsigned short* sb = srcT + (size_t)bb * IHP * IWP * Cc + c;
  const float* ob = offT + (size_t)pos * PSTR;
  float ax = 0.f, ay = 0.f, az = 0.f, aw = 0.f;

  for (int pg = 0; pg < KK4; pg += 4) {
    float4 o01 = *reinterpret_cast<const float4*>(ob + 2 * pg);
    float4 o23 = *reinterpret_cast<const float4*>(ob + 2 * pg + 4);
    float oyv[4] = {o01.x, o01.z, o23.x, o23.z};
    float oxv[4] = {o01.y, o01.w, o23.y, o23.w};
    uint2 v[4][4];
    float wt[4][4];
#pragma unroll
    for (int i = 0; i < 4; ++i) {
      int p = pg + i;
      float py = (float)(h + (p / K_) * DIL_ - PAD_) + oyv[i];
      float px = (float)(w + (p % K_) * DIL_ - PAD_) + oxv[i];
      float y0f = floorf(py), x0f = floorf(px);
      float wy = py - y0f, wx = px - x0f;
      int y0 = (int)y0f, x0 = (int)x0f;
#pragma unroll
      for (int dy = 0; dy < 2; ++dy) {
        int yi = y0 + dy;
        bool yv = (unsigned)yi < (unsigned)Hc;
        int yc = min(max(yi, 0), Hc - 1);
        float wyv = dy ? wy : 1.f - wy;
#pragma unroll
        for (int dx = 0; dx < 2; ++dx) {
          int xi = x0 + dx;
          bool xv = (unsigned)xi < (unsigned)Wc;
          int xc = min(max(xi, 0), Wc - 1);
          wt[i][dy * 2 + dx] = (yv && xv) ? wyv * (dx ? wx : 1.f - wx) : 0.f;
          v[i][dy * 2 + dx] = *reinterpret_cast<const uint2*>(
              sb + ((size_t)(yc + IPADP) * IWP + (xc + IPADP)) * Cc);
        }
      }
    }
#pragma unroll
    for (int i = 0; i < 4; ++i) {
      int p = pg + i;
      float4 d = *reinterpret_cast<const float4*>(dwt + (size_t)p * Cc + c);
      float sx = 0.f, sy = 0.f, sz = 0.f, sw = 0.f;
#pragma unroll
      for (int q = 0; q < 4; ++q) {
        float wq_ = wt[i][q];
        sx += wq_ * bf2f((unsigned short)(v[i][q].x & 0xffffu));
        sy += wq_ * bf2f((unsigned short)(v[i][q].x >> 16));
        sz += wq_ * bf2f((unsigned short)(v[i][q].y & 0xffffu));
        sw += wq_ * bf2f((unsigned short)(v[i][q].y >> 16));
      }
      ax += sx * d.x; ay += sy * d.y; az += sz * d.z; aw += sw * d.w;
    }
  }
  // tail tap (KK % 4 == 1 for K=5,7)
  {
    int p = KK - 1;
    float oy = ob[2 * p], ox = ob[2 * p + 1];
    float py = (float)(h + (p / K_) * DIL_ - PAD_) + oy;
    float px = (float)(w + (p % K_) * DIL_ - PAD_) + ox;
    float y0f = floorf(py), x0f = floorf(px);
    float wy = py - y0f, wx = px - x0f;
    int y0 = (int)y0f, x0 = (int)x0f;
    uint2 v[4]; float wt[4];
#pragma unroll
    for (int dy = 0; dy < 2; ++dy) {
      int yi = y0 + dy;
      bool yv = (unsigned)yi < (unsigned)Hc;
      int yc = min(max(yi, 0), Hc - 1);
      float wyv = dy ? wy : 1.f - wy;
#pragma unroll
      for (int dx = 0; dx < 2; ++dx) {
        int xi = x0 + dx;
        bool xv = (unsigned)xi < (unsigned)Wc;
        int xc = min(max(xi, 0), Wc - 1);
        wt[dy * 2 + dx] = (yv && xv) ? wyv * (dx ? wx : 1.f - wx) : 0.f;
        v[dy * 2 + dx] = *reinterpret_cast<const uint2*>(
            sb + ((size_t)(yc + IPADP) * IWP + (xc + IPADP)) * Cc);
      }
    }
    float4 d = *reinterpret_cast<const float4*>(dwt + (size_t)p * Cc + c);
    float sx = 0.f, sy = 0.f, sz = 0.f, sw = 0.f;
#pragma unroll
    for (int q = 0; q < 4; ++q) {
      sx += wt[q] * bf2f((unsigned short)(v[q].x & 0xffffu));
      sy += wt[q] * bf2f((unsigned short)(v[q].x >> 16));
      sz += wt[q] * bf2f((unsigned short)(v[q].y & 0xffffu));
      sw += wt[q] * bf2f((unsigned short)(v[q].y >> 16));
    }
    ax += sx * d.x; ay += sy * d.y; az += sz * d.z; aw += sw * d.w;
  }

  ax += dbq[c]; ay += dbq[c + 1]; az += dbq[c + 2]; aw += dbq[c + 3];
  if (dst) {
    float* d = dst + (size_t)bb * Cc * HWc + hw;
    d[(c + 0) * HWc] = ax; d[(c + 1) * HWc] = ay;
    d[(c + 2) * HWc] = az; d[(c + 3) * HWc] = aw;
  }
  if (dstPad) {
    unsigned short t4[4] = {f2bf(ax), f2bf(ay), f2bf(az), f2bf(aw)};
    unsigned short* tb = dstPad + (((size_t)bb * (Hc + 2 * OPADP) + h + OPADP) * OWP + w + OPADP) * Cc + c;
    *reinterpret_cast<uint2*>(tb) = *reinterpret_cast<const uint2*>(t4);
  }
}

// ---------------- MLP: LN2 + f1 (96->4), y2 in bf16 NHWC ----------------
__global__ __launch_bounds__(256) void k_mlp1(const unsigned short* __restrict__ y2N,
                                              const float* __restrict__ g,
                                              const float* __restrict__ b,
                                              const float* __restrict__ f1wq,
                                              const float* __restrict__ f1bq,
                                              float* __restrict__ z4) {
  int pos = blockIdx.x * 256 + threadIdx.x;
  int bb = pos / HWc, hw = pos % HWc;
  const unsigned short* yb = y2N + (size_t)pos * Cc;
  float vv[96];
  float s = 0.f, s2 = 0.f;
#pragma unroll
  for (int q = 0; q < 12; ++q) {
    bf16x8 t = *reinterpret_cast<const bf16x8*>(yb + q * 8);
    union { bf16x8 v; unsigned short s[8]; } u; u.v = t;
#pragma unroll
    for (int j = 0; j < 8; ++j) {
      float f = bf2f(u.s[j]);
      vv[q * 8 + j] = f; s += f; s2 += f * f;
    }
  }
  float mu  = s * (1.f / Cc);
  float var = fmaxf(s2 * (1.f / Cc) - mu * mu, 0.f);
  float rs  = rsqrtf(var + EPSc);
  float a0 = 0.f, a1 = 0.f, a2 = 0.f, a3 = 0.f;
#pragma unroll
  for (int c = 0; c < 96; ++c) {
    float t = (vv[c] - mu) * rs * g[c] + b[c];
    a0 += t * f1wq[0 * Cc + c];
    a1 += t * f1wq[1 * Cc + c];
    a2 += t * f1wq[2 * Cc + c];
    a3 += t * f1wq[3 * Cc + c];
  }
  float* zb = z4 + (size_t)bb * 4 * HWc + hw;
  zb[0 * HWc] = a0 + f1bq[0];
  zb[1 * HWc] = a1 + f1bq[1];
  zb[2 * HWc] = a2 + f1bq[2];
  zb[3 * HWc] = a3 + f1bq[3];
}

// ---------------- MLP: depthwise 3x3 (4 ch) + GELU ----------------
__global__ __launch_bounds__(256) void k_mlp_dw(const float* __restrict__ z4,
                                                const float* __restrict__ dwwq,
                                                const float* __restrict__ dwbq,
                                                float* __restrict__ z4b) {
  int tid = blockIdx.x * 256 + threadIdx.x;
  int hw = tid % HWc;
  int bj = tid / HWc;
  int j = bj % 4;
  int h = hw / Wc, w = hw % Wc;
  const float* zb = z4 + (size_t)bj * HWc;
  float s = 0.f;
#pragma unroll
  for (int ky = 0; ky < 3; ++ky) {
    int y = h + ky - 1;
    if ((unsigned)y >= (unsigned)Hc) continue;
#pragma unroll
    for (int kx = 0; kx < 3; ++kx) {
      int x = w + kx - 1;
      if ((unsigned)x >= (unsigned)Wc) continue;
      s += zb[y * Wc + x] * dwwq[j * 9 + ky * 3 + kx];
    }
  }
  z4b[tid] = gelu_exact(s + dwbq[j]);
}

// ---------------- MLP: f2 (4->96) + ls2 + residual add into out ----------------
__global__ __launch_bounds__(256) void k_mlp2(const float* __restrict__ z4b,
                                              const float* __restrict__ f2wq,
                                              const float* __restrict__ f2bq,
                                              const float* __restrict__ ls2q,
                                              float* __restrict__ out) {
  int pos = blockIdx.x * 256 + threadIdx.x;
  int bb = pos / HWc, hw = pos % HWc;
  const float* zb = z4b + (size_t)bb * 4 * HWc + hw;
  float z0 = zb[0 * HWc], z1 = zb[1 * HWc], z2 = zb[2 * HWc], z3 = zb[3 * HWc];
  float* ob = out + (size_t)bb * Cc * HWc + hw;
  for (int o = 0; o < Cc; ++o) {
    float s = f2bq[o] + z0 * f2wq[o * 4 + 0] + z1 * f2wq[o * 4 + 1]
                      + z2 * f2wq[o * 4 + 2] + z3 * f2wq[o * 4 + 3];
    ob[o * HWc] += ls2q[o] * s;
  }
}

}  // namespace

extern "C" void kernel_launch(void* const* d_in, const int* in_sizes, int n_in,
                              void* d_out, int out_size, void* d_ws, size_t ws_size,
                              hipStream_t stream) {
  (void)in_sizes; (void)n_in; (void)out_size; (void)ws_size;
  const float* x   = (const float*)d_in[0];
  const float* g1n = (const float*)d_in[1];
  const float* b1n = (const float*)d_in[2];
  const float* p1w = (const float*)d_in[3];
  const float* p1b = (const float*)d_in[4];
  const float* o0w = (const float*)d_in[5];
  const float* o0b = (const float*)d_in[6];
  const float* d0w = (const float*)d_in[7];
  const float* d0b = (const float*)d_in[8];
  const float* o1w = (const float*)d_in[9];
  const float* o1b = (const float*)d_in[10];
  const float* d1w = (const float*)d_in[11];
  const float* d1b = (const float*)d_in[12];
  const float* c1w = (const float*)d_in[13];
  const float* c1b = (const float*)d_in[14];
  const float* p2w = (const float*)d_in[15];
  const float* p2b = (const float*)d_in[16];
  const float* ls1 = (const float*)d_in[17];
  const float* g2n = (const float*)d_in[18];
  const float* b2n = (const float*)d_in[19];
  const float* f1w = (const float*)d_in[20];
  const float* f1b = (const float*)d_in[21];
  const float* dww = (const float*)d_in[22];
  const float* dwb = (const float*)d_in[23];
  const float* f2w = (const float*)d_in[24];
  const float* f2b = (const float*)d_in[25];
  const float* ls2 = (const float*)d_in[26];
  float* out = (float*)d_out;
  float* ws  = (float*)d_ws;

  float* off0t = ws;                                  size_t o_ = (size_t)Nc * 64;
  float* off1t = ws + o_;                             o_ += (size_t)Nc * 112;
  float* z4    = ws + o_;                             o_ += (size_t)Bc * 4 * HWc;
  float* z4b   = ws + o_;                             o_ += (size_t)Bc * 4 * HWc;
  float* dwt0  = ws + o_;                             o_ += 25 * Cc;
  float* dwt1  = ws + o_;                             o_ += 49 * Cc;
  unsigned short* yln_n  = (unsigned short*)(ws + o_); o_ += (size_t)Nc * Cc / 2;
  unsigned short* a1_n   = (unsigned short*)(ws + o_); o_ += (size_t)Nc * Cc / 2;
  unsigned short* A_n    = (unsigned short*)(ws + o_); o_ += (size_t)Nc * Cc / 2;
  unsigned short* y2_n   = (unsigned short*)(ws + o_); o_ += (size_t)Nc * Cc / 2;
  unsigned short* u_pad  = (unsigned short*)(ws + o_); o_ += (size_t)Bc * 60 * 60 * Cc / 2;
  unsigned short* a0_pad = (unsigned short*)(ws + o_); o_ += (size_t)Bc * 74 * 74 * Cc / 2;
  unsigned short* wpk0   = (unsigned short*)(ws + o_); o_ += (size_t)25 * 3 * 4 * 512 / 2;
  unsigned short* wpk1   = (unsigned short*)(ws + o_); o_ += (size_t)49 * 3 * 7 * 512 / 2;
  unsigned short* wpkp1  = (unsigned short*)(ws + o_); o_ += (size_t)3 * 6 * 512 / 2;
  unsigned short* wpkc1  = (unsigned short*)(ws + o_); o_ += (size_t)3 * 6 * 512 / 2;
  unsigned short* wpkp2  = (unsigned short*)(ws + o_); o_ += (size_t)3 * 6 * 512 / 2;

  dim3 b256(256, 1, 1);

  hipMemsetAsync(u_pad, 0, (size_t)Bc * 60 * 60 * Cc * sizeof(unsigned short), stream);
  hipMemsetAsync(a0_pad, 0, (size_t)Bc * 74 * 74 * Cc * sizeof(unsigned short), stream);
  hipLaunchKernelGGL((k_pack_w<5, 4, 50>), dim3((25 * 3 * 4 * 512 + 255) / 256), b256, 0, stream, o0w, wpk0);
  hipLaunchKernelGGL((k_pack_w<7, 7, 98>), dim3((49 * 3 * 7 * 512 + 255) / 256), b256, 0, stream, o1w, wpk1);
  hipLaunchKernelGGL((k_pack_w<1, 6, 96>), dim3((3 * 6 * 512 + 255) / 256), b256, 0, stream, p1w, wpkp1);
  hipLaunchKernelGGL((k_pack_w<1, 6, 96>), dim3((3 * 6 * 512 + 255) / 256), b256, 0, stream, c1w, wpkc1);
  hipLaunchKernelGGL((k_pack_w<1, 6, 96>), dim3((3 * 6 * 512 + 255) / 256), b256, 0, stream, p2w, wpkp2);
  hipLaunchKernelGGL(k_pack_dwt, dim3((25 * Cc + 255) / 256), b256, 0, stream, d0w, dwt0, 25);
  hipLaunchKernelGGL(k_pack_dwt, dim3((49 * Cc + 255) / 256), b256, 0, stream, d1w, dwt1, 49);

  hipLaunchKernelGGL(k_ln, dim3(Nc / 256), b256, 0, stream, x, g1n, b1n, yln_n);
  hipLaunchKernelGGL((k_pwg<1, 2, 60>), dim3(Nc / 32), b256, 0, stream, yln_n, wpkp1, p1b, u_pad);
  hipLaunchKernelGGL((k_conv_mfma<5, 1, 4, 1, 50, 2, 60, 64>), dim3(Nc / 32), b256, 0, stream,
                     u_pad, wpk0, o0b, off0t);
  hipLaunchKernelGGL((k_deform<5, 1, 2, 2, 60, 9, 74, 64>), dim3(Nc * 24 / 256), b256, 0, stream,
                     u_pad, off0t, dwt0, d0b, (float*)nullptr, a0_pad);
  hipLaunchKernelGGL((k_conv_mfma<7, 3, 7, 2, 98, 9, 74, 112>), dim3(Nc / 32), b256, 0, stream,
                     a0_pad, wpk1, o1b, off1t);
  hipLaunchKernelGGL((k_deform<7, 3, 9, 9, 74, 0, 56, 112>), dim3(Nc * 24 / 256), b256, 0, stream,
                     a0_pad, off1t, dwt1, d1b, (float*)nullptr, a1_n);
  hipLaunchKernelGGL((k_pwg<0, 0, 56>), dim3(Nc / 32), b256, 0, stream, a1_n, wpkc1, c1b, A_n);
  hipLaunchKernelGGL((k_comb<2, 60>), dim3(Nc / 32), b256, 0, stream,
                     u_pad, A_n, wpkp2, p2b, yln_n, ls1, x, out, y2_n);
  hipLaunchKernelGGL(k_mlp1, dim3(Nc / 256), b256, 0, stream, y2_n, g2n, b2n, f1w, f1b, z4);
  hipLaunchKernelGGL(k_mlp_dw, dim3(Nc * 4 / 256), b256, 0, stream, z4, dww, dwb, z4b);
  hipLaunchKernelGGL(k_mlp2, dim3(Nc / 256), b256, 0, stream, z4b, f2w, f2b, ls2, out);
}